// Round 3
// baseline (137.504 us; speedup 1.0000x reference)
//
#include <hip/hip_runtime.h>

typedef __bf16 bf16;
typedef __bf16 bf16x4 __attribute__((ext_vector_type(4)));
typedef __bf16 bf16x8 __attribute__((ext_vector_type(8)));
typedef float f32x4 __attribute__((ext_vector_type(4)));

#define T_SEQ 2048
#define CDIM  1024
#define QKV_LD 3072
#define MEM   256

// global -> LDS direct DMA, 16B per lane. LDS dest is wave-uniform base + lane*16B.
#define GLOAD_LDS16(gp, lp) __builtin_amdgcn_global_load_lds( \
    (const __attribute__((address_space(1))) unsigned int*)(gp), \
    (__attribute__((address_space(3))) unsigned int*)(lp), 16, 0, 0)

#define BAR() do { __builtin_amdgcn_s_barrier(); asm volatile("" ::: "memory"); } while (0)

// ---------------- cast f32 -> bf16 (vectorized x4) ----------------
__global__ __launch_bounds__(256) void cast_f32_bf16_kernel(const float* __restrict__ in,
                                                            bf16* __restrict__ out, int n4) {
    int i = blockIdx.x * 256 + threadIdx.x;
    if (i < n4) {
        float4 v = reinterpret_cast<const float4*>(in)[i];
        bf16x4 o = { (bf16)v.x, (bf16)v.y, (bf16)v.z, (bf16)v.w };
        reinterpret_cast<bf16x4*>(out)[i] = o;
    }
}

// ------------- transpose+cast: W[K][N] f32 -> Wt[N][K] bf16 -------------
__global__ __launch_bounds__(256) void transpose_cast_kernel(const float* __restrict__ W,
                                                             bf16* __restrict__ Wt,
                                                             int K, int N) {
    __shared__ float tile[64][65];
    const int n0 = blockIdx.x * 64;
    const int k0 = blockIdx.y * 64;
    const int t  = threadIdx.x;
    const int tr = t >> 4;
    const int tc = (t & 15) * 4;
#pragma unroll
    for (int it = 0; it < 4; ++it) {
        int r = it * 16 + tr;
        float4 v = *reinterpret_cast<const float4*>(&W[(size_t)(k0 + r) * N + n0 + tc]);
        tile[r][tc + 0] = v.x; tile[r][tc + 1] = v.y;
        tile[r][tc + 2] = v.z; tile[r][tc + 3] = v.w;
    }
    __syncthreads();
#pragma unroll
    for (int it = 0; it < 4; ++it) {
        int n = it * 16 + tr;
        bf16x4 o;
#pragma unroll
        for (int j = 0; j < 4; ++j) o[j] = (bf16)tile[tc + j][n];
        *reinterpret_cast<bf16x4*>(&Wt[(size_t)(n0 + n) * K + k0 + tc]) = o;
    }
}

// ------------- transpose V third of qkv: [T][64] per (b,h) -> Vt[b][h][64][T] -------------
__global__ __launch_bounds__(256) void transpose_v_kernel(const bf16* __restrict__ qkv,
                                                          bf16* __restrict__ Vt) {
    const int bid = blockIdx.x;
    const int tt = bid & 31, h = (bid >> 5) & 15, b = bid >> 9;
    __shared__ bf16 tile[64][72];
    const int i = threadIdx.x;
    {
        const int tr = i >> 2, dc = (i & 3) * 16;
        const bf16* src = qkv + (size_t)(b * T_SEQ + tt * 64 + tr) * QKV_LD + 2 * CDIM + h * 64 + dc;
        *reinterpret_cast<bf16x8*>(&tile[tr][dc])     = *reinterpret_cast<const bf16x8*>(src);
        *reinterpret_cast<bf16x8*>(&tile[tr][dc + 8]) = *reinterpret_cast<const bf16x8*>(src + 8);
    }
    __syncthreads();
    {
        const int dr = i >> 2, tc = (i & 3) * 16;
        bf16x8 o0, o1;
#pragma unroll
        for (int j = 0; j < 8; ++j) { o0[j] = tile[tc + j][dr]; o1[j] = tile[tc + 8 + j][dr]; }
        bf16* dst = Vt + ((size_t)((b * 16 + h) * 64 + dr)) * T_SEQ + tt * 64 + tc;
        *reinterpret_cast<bf16x8*>(dst)     = o0;
        *reinterpret_cast<bf16x8*>(dst + 8) = o1;
    }
}

// ------------- 256x256 8-phase GEMM (T3+T4+T5+T1+swizzle): C = A[M][K] * Bt[N][K]^T -------------
// 512 threads = 8 waves (2M x 4N); per-wave C = 128x64 (8 m-frags x 4 n-frags).
// BK=64, double-buffered 128KiB LDS, counted vmcnt(6), chunk-XOR swizzle (chunk ^= row&7).
__global__ __launch_bounds__(512, 1) void gemm256_kernel(const bf16* __restrict__ A,
                                                         const bf16* __restrict__ Bt,
                                                         bf16* __restrict__ Cb,
                                                         int M, int N, int K) {
    __shared__ bf16 sm[2][2][256][64];   // [buf][mat A/B][row][k]
    const int t    = threadIdx.x;
    const int lane = t & 63;
    const int w    = t >> 6;
    const int wm   = (w >> 2) * 128;     // wave row-half
    const int wn   = (w & 3) * 64;       // wave col-quarter
    const int g    = lane >> 4;
    const int r    = lane & 15;

    // XCD-aware bijective swizzle (gridDim.x % 8 == 0 here: 192)
    const int nwg = gridDim.x, cpx = nwg >> 3;
    const int swz = (blockIdx.x & 7) * cpx + (blockIdx.x >> 3);
    const int ntn = N >> 8;
    const int m0 = (swz / ntn) * 256;
    const int n0 = (swz % ntn) * 256;

    const bf16* Ab = A  + (size_t)m0 * K;
    const bf16* Bb = Bt + (size_t)n0 * K;
    const int NT = K >> 6;               // K-tiles of 64

    // stage one 16KB half-tile: 2 global_load_lds per wave. LDS linear, source pre-swizzled.
#define STAGE(bi, mat, half, kt, gbase) do { \
    _Pragma("unroll") \
    for (int ii = 0; ii < 2; ++ii) { \
        const bf16* _s = (gbase) + (size_t)((half) * 128 + ii * 64 + w * 8 + (lane >> 3)) * K \
                         + (kt) * 64 + ((lane & 7) ^ (lane >> 3)) * 8; \
        GLOAD_LDS16(_s, &sm[bi][mat][(half) * 128 + ii * 64 + w * 8][0]); \
    } } while (0)

    // read-side swizzled chunk offsets (elements): row&7 == r&7 for all frag rows
    const int ch0 = ((g     ) ^ (r & 7)) * 8;
    const int ch1 = ((g ^ 4) ^ (r & 7)) * 8;

    const f32x4 zero4 = {0.f, 0.f, 0.f, 0.f};
    f32x4 acc[8][4];
#pragma unroll
    for (int i = 0; i < 8; ++i)
#pragma unroll
        for (int j = 0; j < 4; ++j) acc[i][j] = zero4;

    bf16x8 afr[8][2], bfr[2][2];

#define MFMA_QUAD(QM, QN) do { \
    __builtin_amdgcn_s_setprio(1); \
    _Pragma("unroll") \
    for (int fm2 = 0; fm2 < 4; ++fm2) \
    _Pragma("unroll") \
    for (int fn2 = 0; fn2 < 2; ++fn2) \
    _Pragma("unroll") \
    for (int kh = 0; kh < 2; ++kh) \
        acc[(QM)*4+fm2][(QN)*2+fn2] = __builtin_amdgcn_mfma_f32_16x16x32_bf16( \
            afr[(QM)*4+fm2][kh], bfr[fn2][kh], acc[(QM)*4+fm2][(QN)*2+fn2], 0, 0, 0); \
    __builtin_amdgcn_s_setprio(0); } while (0)

    // ---- prologue: T0 fully + T1 {A-h0, A-h1, B-h0}; wait T0 landed ----
    STAGE(0, 0, 0, 0, Ab); STAGE(0, 0, 1, 0, Ab);
    STAGE(0, 1, 0, 0, Bb); STAGE(0, 1, 1, 0, Bb);
    if (NT > 1) { STAGE(1, 0, 0, 1, Ab); STAGE(1, 0, 1, 1, Ab); STAGE(1, 1, 0, 1, Bb); }
    if (NT > 1) { asm volatile("s_waitcnt vmcnt(6)" ::: "memory"); }
    else        { asm volatile("s_waitcnt vmcnt(0)" ::: "memory"); }
    __builtin_amdgcn_sched_barrier(0);
    BAR();

    for (int kt = 0; kt < NT; ++kt) {
        const int cur = kt & 1, nxt = cur ^ 1;
        // ---- phase 1: read all A-frags + B qn0-frags; stage (t+1).B-h1 ----
#pragma unroll
        for (int fm = 0; fm < 8; ++fm) {
            afr[fm][0] = *reinterpret_cast<const bf16x8*>(&sm[cur][0][wm + fm * 16 + r][ch0]);
            afr[fm][1] = *reinterpret_cast<const bf16x8*>(&sm[cur][0][wm + fm * 16 + r][ch1]);
        }
#pragma unroll
        for (int fn = 0; fn < 2; ++fn) {
            bfr[fn][0] = *reinterpret_cast<const bf16x8*>(&sm[cur][1][wn + fn * 16 + r][ch0]);
            bfr[fn][1] = *reinterpret_cast<const bf16x8*>(&sm[cur][1][wn + fn * 16 + r][ch1]);
        }
        if (kt + 1 < NT) STAGE(nxt, 1, 1, kt + 1, Bb);
        BAR();
        MFMA_QUAD(0, 0);
        BAR();
        // ---- phase 2: stage (t+2).A-h0 (cur buf: A reads done at ph1) ----
        if (kt + 2 < NT) STAGE(cur, 0, 0, kt + 2, Ab);
        BAR();
        MFMA_QUAD(1, 0);
        BAR();
        // ---- phase 3: read B qn1-frags; stage (t+2).A-h1 ----
#pragma unroll
        for (int fn = 0; fn < 2; ++fn) {
            bfr[fn][0] = *reinterpret_cast<const bf16x8*>(&sm[cur][1][wn + 32 + fn * 16 + r][ch0]);
            bfr[fn][1] = *reinterpret_cast<const bf16x8*>(&sm[cur][1][wn + 32 + fn * 16 + r][ch1]);
        }
        if (kt + 2 < NT) STAGE(cur, 0, 1, kt + 2, Ab);
        BAR();
        MFMA_QUAD(1, 1);
        BAR();
        // ---- phase 4: stage (t+2).B-h0; MFMA; counted vmcnt; tile barrier ----
        if (kt + 2 < NT) STAGE(cur, 1, 0, kt + 2, Bb);
        BAR();
        MFMA_QUAD(0, 1);
        if (kt == NT - 2)      { asm volatile("s_waitcnt vmcnt(0)" ::: "memory"); }
        else if (kt < NT - 2)  { asm volatile("s_waitcnt vmcnt(6)" ::: "memory"); }
        __builtin_amdgcn_sched_barrier(0);
        BAR();
    }

    // ---- epilogue: C/D layout col = lane&15, row = 4*(lane>>4)+e ----
#pragma unroll
    for (int fm = 0; fm < 8; ++fm)
#pragma unroll
        for (int fn = 0; fn < 4; ++fn)
#pragma unroll
            for (int e = 0; e < 4; ++e) {
                int row = m0 + wm + fm * 16 + g * 4 + e;
                int col = n0 + wn + fn * 16 + r;
                Cb[(size_t)row * N + col] = (bf16)acc[fm][fn][e];
            }
#undef STAGE
#undef MFMA_QUAD
}

// ------------- GEMM: C[M][N] = A[M][K] * Bt[N][K]^T  (m97 structure, proj) -------------
template<bool OUT_BF16>
__global__ __launch_bounds__(256) void gemm_bt_kernel(const bf16* __restrict__ A,
                                                      const bf16* __restrict__ Bt,
                                                      bf16* __restrict__ Cb,
                                                      float* __restrict__ Cf,
                                                      int M, int N, int K) {
    __shared__ bf16 As[128 * 32];
    __shared__ bf16 Bs[128 * 32];
    const int t    = threadIdx.x;
    const int lane = t & 63;
    const int w    = t >> 6;
    const int wm   = (w >> 1) * 64;
    const int wn   = (w & 1) * 64;
    const int g    = lane >> 4;
    const int r    = lane & 15;
    const int m0   = blockIdx.y * 128;
    const int n0   = blockIdx.x * 128;

    const bf16* Ab = A  + (size_t)m0 * K;
    const bf16* Bb = Bt + (size_t)n0 * K;
    const bf16* Ag0 = Ab + (size_t)(w * 32 + (lane >> 2)) * K + (lane & 3) * 8;
    const bf16* Ag1 = Ab + (size_t)(w * 32 + 16 + (lane >> 2)) * K + (lane & 3) * 8;
    const bf16* Bg0 = Bb + (size_t)(w * 32 + (lane >> 2)) * K + (lane & 3) * 8;
    const bf16* Bg1 = Bb + (size_t)(w * 32 + 16 + (lane >> 2)) * K + (lane & 3) * 8;

    bf16* ldsA0 = As + (w * 32) * 32;
    bf16* ldsA1 = As + (w * 32 + 16) * 32;
    bf16* ldsB0 = Bs + (w * 32) * 32;
    bf16* ldsB1 = Bs + (w * 32 + 16) * 32;

    const f32x4 zero4 = {0.f, 0.f, 0.f, 0.f};
    f32x4 acc[4][4];
#pragma unroll
    for (int i = 0; i < 4; ++i)
#pragma unroll
        for (int j = 0; j < 4; ++j) acc[i][j] = zero4;

    for (int k0 = 0; k0 < K; k0 += 32) {
        __syncthreads();
        GLOAD_LDS16(Ag0 + k0, ldsA0);
        GLOAD_LDS16(Ag1 + k0, ldsA1);
        GLOAD_LDS16(Bg0 + k0, ldsB0);
        GLOAD_LDS16(Bg1 + k0, ldsB1);
        __syncthreads();

        bf16x8 af[4], bfr[4];
#pragma unroll
        for (int i = 0; i < 4; ++i) {
            af[i]  = *reinterpret_cast<const bf16x8*>(&As[(wm + i * 16 + r) * 32 + g * 8]);
            bfr[i] = *reinterpret_cast<const bf16x8*>(&Bs[(wn + i * 16 + r) * 32 + g * 8]);
        }
#pragma unroll
        for (int i = 0; i < 4; ++i)
#pragma unroll
            for (int j = 0; j < 4; ++j)
                acc[i][j] = __builtin_amdgcn_mfma_f32_16x16x32_bf16(af[i], bfr[j], acc[i][j], 0, 0, 0);
    }

#pragma unroll
    for (int i = 0; i < 4; ++i)
#pragma unroll
        for (int j = 0; j < 4; ++j)
#pragma unroll
            for (int e = 0; e < 4; ++e) {
                int row = m0 + wm + i * 16 + g * 4 + e;
                int col = n0 + wn + j * 16 + r;
                if constexpr (OUT_BF16) Cb[(size_t)row * N + col] = (bf16)acc[i][j][e];
                else                    Cf[(size_t)row * N + col] = acc[i][j][e];
            }
}

// ------------- banded flash attention (V^T vector loads) -------------
__global__ __launch_bounds__(256) void attn_kernel(const bf16* __restrict__ qkv,
                                                   const bf16* __restrict__ Vt,
                                                   bf16* __restrict__ y) {
    const int wid  = blockIdx.x * 4 + (threadIdx.x >> 6);
    const int lane = threadIdx.x & 63;
    const int bh = wid >> 7;
    const int qt = wid & 127;
    const int b = bh >> 4, h = bh & 15;
    const int q0 = qt * 16;
    const int g = lane >> 4, c = lane & 15;
    const float NEG_INF = -__builtin_inff();

    const bf16* base = qkv + (size_t)b * T_SEQ * QKV_LD;
    const bf16* Qb = base + h * 64;
    const bf16* Kb = base + CDIM + h * 64;
    const bf16* Vtb = Vt + (size_t)(b * 16 + h) * 64 * T_SEQ;
    const int q = q0 + c;

    const bf16x8 qf0 = *reinterpret_cast<const bf16x8*>(Qb + (size_t)q * QKV_LD + g * 8);
    const bf16x8 qf1 = *reinterpret_cast<const bf16x8*>(Qb + (size_t)q * QKV_LD + 32 + g * 8);

    const f32x4 zero4 = {0.f, 0.f, 0.f, 0.f};
    f32x4 o[4];
#pragma unroll
    for (int cb = 0; cb < 4; ++cb) o[cb] = zero4;
    float m_run = NEG_INF, l_run = 0.f;

    const int jstart = (q0 - MEM > 0) ? (q0 - MEM) : 0;
    for (int j0 = jstart; j0 < q0 + 16; j0 += 32) {
        const int kr0 = j0 + c;
        int kr1 = j0 + 16 + c; kr1 = kr1 < T_SEQ ? kr1 : T_SEQ - 1;
        bf16x8 kf00 = *reinterpret_cast<const bf16x8*>(Kb + (size_t)kr0 * QKV_LD + g * 8);
        bf16x8 kf01 = *reinterpret_cast<const bf16x8*>(Kb + (size_t)kr0 * QKV_LD + 32 + g * 8);
        bf16x8 kf10 = *reinterpret_cast<const bf16x8*>(Kb + (size_t)kr1 * QKV_LD + g * 8);
        bf16x8 kf11 = *reinterpret_cast<const bf16x8*>(Kb + (size_t)kr1 * QKV_LD + 32 + g * 8);
        f32x4 s0 = __builtin_amdgcn_mfma_f32_16x16x32_bf16(kf00, qf0, zero4, 0, 0, 0);
        s0 = __builtin_amdgcn_mfma_f32_16x16x32_bf16(kf01, qf1, s0, 0, 0, 0);
        f32x4 s1 = __builtin_amdgcn_mfma_f32_16x16x32_bf16(kf10, qf0, zero4, 0, 0, 0);
        s1 = __builtin_amdgcn_mfma_f32_16x16x32_bf16(kf11, qf1, s1, 0, 0, 0);

        float mt = NEG_INF;
#pragma unroll
        for (int e = 0; e < 4; ++e) {
            int k0i = j0 + 4 * g + e;
            int k1i = k0i + 16;
            float v0 = (k0i <= q && k0i >= q - MEM) ? s0[e] * 0.125f : NEG_INF;
            float v1 = (k1i <= q && k1i >= q - MEM) ? s1[e] * 0.125f : NEG_INF;
            s0[e] = v0; s1[e] = v1;
            mt = fmaxf(mt, fmaxf(v0, v1));
        }
        mt = fmaxf(mt, __shfl_xor(mt, 16, 64));
        mt = fmaxf(mt, __shfl_xor(mt, 32, 64));
        const float mnew = fmaxf(m_run, mt);
        const float corr = __expf(m_run - mnew);

        float ps = 0.f;
        bf16x8 pav;
#pragma unroll
        for (int e = 0; e < 4; ++e) {
            float e0 = __expf(s0[e] - mnew);
            float e1 = __expf(s1[e] - mnew);
            ps += e0 + e1;
            pav[e]     = (bf16)e0;
            pav[4 + e] = (bf16)e1;
        }
        ps += __shfl_xor(ps, 16, 64);
        ps += __shfl_xor(ps, 32, 64);
        l_run = l_run * corr + ps;
        m_run = mnew;

        float cr[4];
#pragma unroll
        for (int e = 0; e < 4; ++e) cr[e] = __shfl(corr, 4 * g + e, 64);
#pragma unroll
        for (int cb = 0; cb < 4; ++cb) {
            o[cb][0] *= cr[0]; o[cb][1] *= cr[1]; o[cb][2] *= cr[2]; o[cb][3] *= cr[3];
        }

        // PV: V-frag rows j0+4g..+3 and j0+16+4g..+3 at col d = cb*16+c -> two bf16x4 from V^T
#pragma unroll
        for (int cb = 0; cb < 4; ++cb) {
            const bf16* vrow = Vtb + (size_t)(cb * 16 + c) * T_SEQ;
            bf16x4 va = *reinterpret_cast<const bf16x4*>(vrow + j0 + 4 * g);
            bf16x4 vb2 = *reinterpret_cast<const bf16x4*>(vrow + j0 + 16 + 4 * g);
            bf16x8 vf = { va[0], va[1], va[2], va[3], vb2[0], vb2[1], vb2[2], vb2[3] };
            o[cb] = __builtin_amdgcn_mfma_f32_16x16x32_bf16(pav, vf, o[cb], 0, 0, 0);
        }
    }

    float lr[4];
#pragma unroll
    for (int e = 0; e < 4; ++e) lr[e] = __shfl(l_run, 4 * g + e, 64);
#pragma unroll
    for (int cb = 0; cb < 4; ++cb)
#pragma unroll
        for (int e = 0; e < 4; ++e)
            y[(size_t)(b * T_SEQ + q0 + 4 * g + e) * CDIM + h * 64 + cb * 16 + c] =
                (bf16)(o[cb][e] / lr[e]);
}

// ---------------- launch ----------------
extern "C" void kernel_launch(void* const* d_in, const int* in_sizes, int n_in,
                              void* d_out, int out_size, void* d_ws, size_t ws_size,
                              hipStream_t stream) {
    const float* x      = (const float*)d_in[0];
    const float* W_attn = (const float*)d_in[1];
    const float* W_proj = (const float*)d_in[2];
    float* out = (float*)d_out;

    char* ws = (char*)d_ws;
    bf16* xb   = (bf16*)(ws);                  //  4096x1024 bf16 =  8 MiB (dead after qkv GEMM)
    bf16* WaT  = (bf16*)(ws + 8388608);        //  3072x1024 bf16 =  6 MiB
    bf16* WpT  = (bf16*)(ws + 14680064);       //  1024x1024 bf16 =  2 MiB
    bf16* qkv  = (bf16*)(ws + 16777216);       //  4096x3072 bf16 = 24 MiB
    bf16* yatt = (bf16*)(ws + 41943040);       //  4096x1024 bf16 =  8 MiB
    bf16* Vt   = xb;                           //  reuse xb region: 2x16x64x2048 bf16 = 8 MiB

    cast_f32_bf16_kernel<<<4096, 256, 0, stream>>>(x, xb, 1048576);
    transpose_cast_kernel<<<dim3(48, 16), 256, 0, stream>>>(W_attn, WaT, 1024, 3072);
    transpose_cast_kernel<<<dim3(16, 16), 256, 0, stream>>>(W_proj, WpT, 1024, 1024);

    gemm256_kernel<<<192, 512, 0, stream>>>(xb, WaT, qkv, 4096, 3072, 1024);
    transpose_v_kernel<<<1024, 256, 0, stream>>>(qkv, Vt);
    attn_kernel<<<1024, 256, 0, stream>>>(qkv, Vt, yatt);
    gemm_bt_kernel<false><<<dim3(8, 32), 256, 0, stream>>>(yatt, WpT, nullptr, out, 4096, 1024, 1024);
}

// Round 4
// 111.996 us; speedup vs baseline: 1.2278x; 1.2278x over previous
//
#include <hip/hip_runtime.h>

typedef __bf16 bf16;
typedef __bf16 bf16x4 __attribute__((ext_vector_type(4)));
typedef __bf16 bf16x8 __attribute__((ext_vector_type(8)));
typedef float f32x4 __attribute__((ext_vector_type(4)));

#define T_SEQ 2048
#define CDIM  1024
#define QKV_LD 3072
#define MEM   256

// global -> LDS direct DMA, 16B per lane. LDS dest is wave-uniform base + lane*16B.
#define GLOAD_LDS16(gp, lp) __builtin_amdgcn_global_load_lds( \
    (const __attribute__((address_space(1))) unsigned int*)(gp), \
    (__attribute__((address_space(3))) unsigned int*)(lp), 16, 0, 0)

#define BAR() do { __builtin_amdgcn_s_barrier(); asm volatile("" ::: "memory"); } while (0)

// ---------------- cast f32 -> bf16 (vectorized x4) ----------------
__global__ __launch_bounds__(256) void cast_f32_bf16_kernel(const float* __restrict__ in,
                                                            bf16* __restrict__ out, int n4) {
    int i = blockIdx.x * 256 + threadIdx.x;
    if (i < n4) {
        float4 v = reinterpret_cast<const float4*>(in)[i];
        bf16x4 o = { (bf16)v.x, (bf16)v.y, (bf16)v.z, (bf16)v.w };
        reinterpret_cast<bf16x4*>(out)[i] = o;
    }
}

// ------------- transpose+cast: W[K][N] f32 -> Wt[N][K] bf16 -------------
__global__ __launch_bounds__(256) void transpose_cast_kernel(const float* __restrict__ W,
                                                             bf16* __restrict__ Wt,
                                                             int K, int N) {
    __shared__ float tile[64][65];
    const int n0 = blockIdx.x * 64;
    const int k0 = blockIdx.y * 64;
    const int t  = threadIdx.x;
    const int tr = t >> 4;
    const int tc = (t & 15) * 4;
#pragma unroll
    for (int it = 0; it < 4; ++it) {
        int r = it * 16 + tr;
        float4 v = *reinterpret_cast<const float4*>(&W[(size_t)(k0 + r) * N + n0 + tc]);
        tile[r][tc + 0] = v.x; tile[r][tc + 1] = v.y;
        tile[r][tc + 2] = v.z; tile[r][tc + 3] = v.w;
    }
    __syncthreads();
#pragma unroll
    for (int it = 0; it < 4; ++it) {
        int n = it * 16 + tr;
        bf16x4 o;
#pragma unroll
        for (int j = 0; j < 4; ++j) o[j] = (bf16)tile[tc + j][n];
        *reinterpret_cast<bf16x4*>(&Wt[(size_t)(n0 + n) * K + k0 + tc]) = o;
    }
}

// ------------- 256x256 8-phase GEMM (T3+T4+T5+T1+swizzle): C = A[M][K] * Bt[N][K]^T -------------
__global__ __launch_bounds__(512, 1) void gemm256_kernel(const bf16* __restrict__ A,
                                                         const bf16* __restrict__ Bt,
                                                         bf16* __restrict__ Cb,
                                                         int M, int N, int K) {
    __shared__ bf16 sm[2][2][256][64];   // [buf][mat A/B][row][k]
    const int t    = threadIdx.x;
    const int lane = t & 63;
    const int w    = t >> 6;
    const int wm   = (w >> 2) * 128;     // wave row-half
    const int wn   = (w & 3) * 64;       // wave col-quarter
    const int g    = lane >> 4;
    const int r    = lane & 15;

    const int nwg = gridDim.x, cpx = nwg >> 3;
    const int swz = (blockIdx.x & 7) * cpx + (blockIdx.x >> 3);
    const int ntn = N >> 8;
    const int m0 = (swz / ntn) * 256;
    const int n0 = (swz % ntn) * 256;

    const bf16* Ab = A  + (size_t)m0 * K;
    const bf16* Bb = Bt + (size_t)n0 * K;
    const int NT = K >> 6;               // K-tiles of 64

#define STAGE(bi, mat, half, kt, gbase) do { \
    _Pragma("unroll") \
    for (int ii = 0; ii < 2; ++ii) { \
        const bf16* _s = (gbase) + (size_t)((half) * 128 + ii * 64 + w * 8 + (lane >> 3)) * K \
                         + (kt) * 64 + ((lane & 7) ^ (lane >> 3)) * 8; \
        GLOAD_LDS16(_s, &sm[bi][mat][(half) * 128 + ii * 64 + w * 8][0]); \
    } } while (0)

    const int ch0 = ((g     ) ^ (r & 7)) * 8;
    const int ch1 = ((g ^ 4) ^ (r & 7)) * 8;

    const f32x4 zero4 = {0.f, 0.f, 0.f, 0.f};
    f32x4 acc[8][4];
#pragma unroll
    for (int i = 0; i < 8; ++i)
#pragma unroll
        for (int j = 0; j < 4; ++j) acc[i][j] = zero4;

    bf16x8 afr[8][2], bfr[2][2];

#define MFMA_QUAD(QM, QN) do { \
    __builtin_amdgcn_s_setprio(1); \
    _Pragma("unroll") \
    for (int fm2 = 0; fm2 < 4; ++fm2) \
    _Pragma("unroll") \
    for (int fn2 = 0; fn2 < 2; ++fn2) \
    _Pragma("unroll") \
    for (int kh = 0; kh < 2; ++kh) \
        acc[(QM)*4+fm2][(QN)*2+fn2] = __builtin_amdgcn_mfma_f32_16x16x32_bf16( \
            afr[(QM)*4+fm2][kh], bfr[fn2][kh], acc[(QM)*4+fm2][(QN)*2+fn2], 0, 0, 0); \
    __builtin_amdgcn_s_setprio(0); } while (0)

    STAGE(0, 0, 0, 0, Ab); STAGE(0, 0, 1, 0, Ab);
    STAGE(0, 1, 0, 0, Bb); STAGE(0, 1, 1, 0, Bb);
    if (NT > 1) { STAGE(1, 0, 0, 1, Ab); STAGE(1, 0, 1, 1, Ab); STAGE(1, 1, 0, 1, Bb); }
    if (NT > 1) { asm volatile("s_waitcnt vmcnt(6)" ::: "memory"); }
    else        { asm volatile("s_waitcnt vmcnt(0)" ::: "memory"); }
    __builtin_amdgcn_sched_barrier(0);
    BAR();

    for (int kt = 0; kt < NT; ++kt) {
        const int cur = kt & 1, nxt = cur ^ 1;
#pragma unroll
        for (int fm = 0; fm < 8; ++fm) {
            afr[fm][0] = *reinterpret_cast<const bf16x8*>(&sm[cur][0][wm + fm * 16 + r][ch0]);
            afr[fm][1] = *reinterpret_cast<const bf16x8*>(&sm[cur][0][wm + fm * 16 + r][ch1]);
        }
#pragma unroll
        for (int fn = 0; fn < 2; ++fn) {
            bfr[fn][0] = *reinterpret_cast<const bf16x8*>(&sm[cur][1][wn + fn * 16 + r][ch0]);
            bfr[fn][1] = *reinterpret_cast<const bf16x8*>(&sm[cur][1][wn + fn * 16 + r][ch1]);
        }
        if (kt + 1 < NT) STAGE(nxt, 1, 1, kt + 1, Bb);
        BAR();
        MFMA_QUAD(0, 0);
        BAR();
        if (kt + 2 < NT) STAGE(cur, 0, 0, kt + 2, Ab);
        BAR();
        MFMA_QUAD(1, 0);
        BAR();
#pragma unroll
        for (int fn = 0; fn < 2; ++fn) {
            bfr[fn][0] = *reinterpret_cast<const bf16x8*>(&sm[cur][1][wn + 32 + fn * 16 + r][ch0]);
            bfr[fn][1] = *reinterpret_cast<const bf16x8*>(&sm[cur][1][wn + 32 + fn * 16 + r][ch1]);
        }
        if (kt + 2 < NT) STAGE(cur, 0, 1, kt + 2, Ab);
        BAR();
        MFMA_QUAD(1, 1);
        BAR();
        if (kt + 2 < NT) STAGE(cur, 1, 0, kt + 2, Bb);
        BAR();
        MFMA_QUAD(0, 1);
        if (kt == NT - 2)      { asm volatile("s_waitcnt vmcnt(0)" ::: "memory"); }
        else if (kt < NT - 2)  { asm volatile("s_waitcnt vmcnt(6)" ::: "memory"); }
        __builtin_amdgcn_sched_barrier(0);
        BAR();
    }

#pragma unroll
    for (int fm = 0; fm < 8; ++fm)
#pragma unroll
        for (int fn = 0; fn < 4; ++fn)
#pragma unroll
            for (int e = 0; e < 4; ++e) {
                int row = m0 + wm + fm * 16 + g * 4 + e;
                int col = n0 + wn + fn * 16 + r;
                Cb[(size_t)row * N + col] = (bf16)acc[fm][fn][e];
            }
#undef STAGE
#undef MFMA_QUAD
}

// ------------- GEMM: C[M][N] = A[M][K] * Bt[N][K]^T  (m97 structure, proj) -------------
template<bool OUT_BF16>
__global__ __launch_bounds__(256) void gemm_bt_kernel(const bf16* __restrict__ A,
                                                      const bf16* __restrict__ Bt,
                                                      bf16* __restrict__ Cb,
                                                      float* __restrict__ Cf,
                                                      int M, int N, int K) {
    __shared__ bf16 As[128 * 32];
    __shared__ bf16 Bs[128 * 32];
    const int t    = threadIdx.x;
    const int lane = t & 63;
    const int w    = t >> 6;
    const int wm   = (w >> 1) * 64;
    const int wn   = (w & 1) * 64;
    const int g    = lane >> 4;
    const int r    = lane & 15;
    const int m0   = blockIdx.y * 128;
    const int n0   = blockIdx.x * 128;

    const bf16* Ab = A  + (size_t)m0 * K;
    const bf16* Bb = Bt + (size_t)n0 * K;
    const bf16* Ag0 = Ab + (size_t)(w * 32 + (lane >> 2)) * K + (lane & 3) * 8;
    const bf16* Ag1 = Ab + (size_t)(w * 32 + 16 + (lane >> 2)) * K + (lane & 3) * 8;
    const bf16* Bg0 = Bb + (size_t)(w * 32 + (lane >> 2)) * K + (lane & 3) * 8;
    const bf16* Bg1 = Bb + (size_t)(w * 32 + 16 + (lane >> 2)) * K + (lane & 3) * 8;

    bf16* ldsA0 = As + (w * 32) * 32;
    bf16* ldsA1 = As + (w * 32 + 16) * 32;
    bf16* ldsB0 = Bs + (w * 32) * 32;
    bf16* ldsB1 = Bs + (w * 32 + 16) * 32;

    const f32x4 zero4 = {0.f, 0.f, 0.f, 0.f};
    f32x4 acc[4][4];
#pragma unroll
    for (int i = 0; i < 4; ++i)
#pragma unroll
        for (int j = 0; j < 4; ++j) acc[i][j] = zero4;

    for (int k0 = 0; k0 < K; k0 += 32) {
        __syncthreads();
        GLOAD_LDS16(Ag0 + k0, ldsA0);
        GLOAD_LDS16(Ag1 + k0, ldsA1);
        GLOAD_LDS16(Bg0 + k0, ldsB0);
        GLOAD_LDS16(Bg1 + k0, ldsB1);
        __syncthreads();

        bf16x8 af[4], bfr[4];
#pragma unroll
        for (int i = 0; i < 4; ++i) {
            af[i]  = *reinterpret_cast<const bf16x8*>(&As[(wm + i * 16 + r) * 32 + g * 8]);
            bfr[i] = *reinterpret_cast<const bf16x8*>(&Bs[(wn + i * 16 + r) * 32 + g * 8]);
        }
#pragma unroll
        for (int i = 0; i < 4; ++i)
#pragma unroll
            for (int j = 0; j < 4; ++j)
                acc[i][j] = __builtin_amdgcn_mfma_f32_16x16x32_bf16(af[i], bfr[j], acc[i][j], 0, 0, 0);
    }

#pragma unroll
    for (int i = 0; i < 4; ++i)
#pragma unroll
        for (int j = 0; j < 4; ++j)
#pragma unroll
            for (int e = 0; e < 4; ++e) {
                int row = m0 + wm + i * 16 + g * 4 + e;
                int col = n0 + wn + j * 16 + r;
                if constexpr (OUT_BF16) Cb[(size_t)row * N + col] = (bf16)acc[i][j][e];
                else                    Cf[(size_t)row * N + col] = acc[i][j][e];
            }
}

// ------------- banded flash attention v3: block-level V^T LDS staging -------------
// Block = (b, h, 64 q-rows) = 4 waves x 16 q-rows. V^T window staged in LDS
// (in-kernel transpose); K read from global (coalesced b128, L2-resident).
// PV computed as O^T = mfma(vf, pav): per-lane q = c -> lane-local rescale,
// vectorized bf16x4 output stores; vf = two ds_read_b64 per cb from V^T LDS.
__global__ __launch_bounds__(256) void attn_kernel(const bf16* __restrict__ qkv,
                                                   bf16* __restrict__ y) {
    __shared__ bf16 vt[64][388];         // [d][krel], pad 388 (=4*97) vs 384 window
    const int bid  = blockIdx.x;
    const int bh   = bid >> 5;
    const int qblk = bid & 31;
    const int b = bh >> 4, h = bh & 15;
    const int qb0 = qblk * 64;
    const int wlo = qb0 - 256;           // window start (may be negative)
    const int w    = threadIdx.x >> 6;
    const int lane = threadIdx.x & 63;
    const int g = lane >> 4, c = lane & 15;
    const int q0 = qb0 + w * 16;
    const int q = q0 + c;
    const float NEG_INF = -__builtin_inff();

    const bf16* base = qkv + (size_t)b * T_SEQ * QKV_LD;
    const bf16* Qb = base + h * 64;
    const bf16* Kb = base + CDIM + h * 64;
    const bf16* Vb = base + 2 * CDIM + h * 64;

    // ---- stage V^T: rows [wlo, wlo+384) of V -> vt[d][krel] (edge rows clamped; masked anyway)
#pragma unroll
    for (int it = 0; it < 12; ++it) {
        int idx = it * 256 + threadIdx.x;   // 0..3071 = 384 rows x 8 chunks
        int row = idx >> 3, ch = idx & 7;
        int gk = wlo + row;
        gk = gk < 0 ? 0 : (gk > T_SEQ - 1 ? T_SEQ - 1 : gk);
        bf16x8 v = *reinterpret_cast<const bf16x8*>(Vb + (size_t)gk * QKV_LD + ch * 8);
#pragma unroll
        for (int j = 0; j < 8; ++j) vt[ch * 8 + j][row] = v[j];
    }

    const bf16x8 qf0 = *reinterpret_cast<const bf16x8*>(Qb + (size_t)q * QKV_LD + g * 8);
    const bf16x8 qf1 = *reinterpret_cast<const bf16x8*>(Qb + (size_t)q * QKV_LD + 32 + g * 8);

    __syncthreads();

    const f32x4 zero4 = {0.f, 0.f, 0.f, 0.f};
    f32x4 o[4];
#pragma unroll
    for (int cb = 0; cb < 4; ++cb) o[cb] = zero4;
    float m_run = NEG_INF, l_run = 0.f;

    const int jstart = (q0 - MEM > 0) ? (q0 - MEM) : 0;
    for (int j0 = jstart; j0 < q0 + 16; j0 += 32) {
        // --- S^T = mfma(K, Q) for 32 keys ---
        const int kr0 = j0 + c;
        int kr1 = j0 + 16 + c; kr1 = kr1 < T_SEQ ? kr1 : T_SEQ - 1;
        bf16x8 kf00 = *reinterpret_cast<const bf16x8*>(Kb + (size_t)kr0 * QKV_LD + g * 8);
        bf16x8 kf01 = *reinterpret_cast<const bf16x8*>(Kb + (size_t)kr0 * QKV_LD + 32 + g * 8);
        bf16x8 kf10 = *reinterpret_cast<const bf16x8*>(Kb + (size_t)kr1 * QKV_LD + g * 8);
        bf16x8 kf11 = *reinterpret_cast<const bf16x8*>(Kb + (size_t)kr1 * QKV_LD + 32 + g * 8);
        f32x4 s0 = __builtin_amdgcn_mfma_f32_16x16x32_bf16(kf00, qf0, zero4, 0, 0, 0);
        s0 = __builtin_amdgcn_mfma_f32_16x16x32_bf16(kf01, qf1, s0, 0, 0, 0);
        f32x4 s1 = __builtin_amdgcn_mfma_f32_16x16x32_bf16(kf10, qf0, zero4, 0, 0, 0);
        s1 = __builtin_amdgcn_mfma_f32_16x16x32_bf16(kf11, qf1, s1, 0, 0, 0);

        // --- scale + band mask; S^T value (lane,e) = S[key=j0+4g+e(+16)][q=c] ---
        float mt = NEG_INF;
#pragma unroll
        for (int e = 0; e < 4; ++e) {
            int k0i = j0 + 4 * g + e;
            int k1i = k0i + 16;
            float v0 = (k0i <= q && k0i >= q - MEM) ? s0[e] * 0.125f : NEG_INF;
            float v1 = (k1i <= q && k1i >= q - MEM) ? s1[e] * 0.125f : NEG_INF;
            s0[e] = v0; s1[e] = v1;
            mt = fmaxf(mt, fmaxf(v0, v1));
        }
        mt = fmaxf(mt, __shfl_xor(mt, 16, 64));
        mt = fmaxf(mt, __shfl_xor(mt, 32, 64));
        const float mnew = fmaxf(m_run, mt);
        const float corr = __expf(m_run - mnew);

        float ps = 0.f;
        bf16x8 pav;
#pragma unroll
        for (int e = 0; e < 4; ++e) {
            float e0 = __expf(s0[e] - mnew);
            float e1 = __expf(s1[e] - mnew);
            ps += e0 + e1;
            pav[e]     = (bf16)e0;
            pav[4 + e] = (bf16)e1;
        }
        ps += __shfl_xor(ps, 16, 64);
        ps += __shfl_xor(ps, 32, 64);
        l_run = l_run * corr + ps;
        m_run = mnew;

        // --- O^T rescale: lane-local (q = c for all regs) ---
#pragma unroll
        for (int cb = 0; cb < 4; ++cb) {
            o[cb][0] *= corr; o[cb][1] *= corr; o[cb][2] *= corr; o[cb][3] *= corr;
        }

        // --- PV as O^T = mfma(V-frag, pav): vf[jj] = V[j0+kmap(g,jj)][cb*16+c] ---
        const int jrel = j0 - wlo;
#pragma unroll
        for (int cb = 0; cb < 4; ++cb) {
            const bf16* vr = &vt[cb * 16 + c][jrel + 4 * g];
            bf16x4 va  = *reinterpret_cast<const bf16x4*>(vr);
            bf16x4 vb2 = *reinterpret_cast<const bf16x4*>(vr + 16);
            bf16x8 vf = { va[0], va[1], va[2], va[3], vb2[0], vb2[1], vb2[2], vb2[3] };
            o[cb] = __builtin_amdgcn_mfma_f32_16x16x32_bf16(vf, pav, o[cb], 0, 0, 0);
        }
    }

    // --- epilogue: o[cb][e] = O[q=q0+c][d = cb*16+4g+e]; lane-local divide; bf16x4 stores ---
    const float linv = 1.0f / l_run;
    bf16* yr = y + (size_t)(b * T_SEQ + q) * CDIM + h * 64 + 4 * g;
#pragma unroll
    for (int cb = 0; cb < 4; ++cb) {
        bf16x4 ov = { (bf16)(o[cb][0] * linv), (bf16)(o[cb][1] * linv),
                      (bf16)(o[cb][2] * linv), (bf16)(o[cb][3] * linv) };
        *reinterpret_cast<bf16x4*>(yr + cb * 16) = ov;
    }
}

// ---------------- launch ----------------
extern "C" void kernel_launch(void* const* d_in, const int* in_sizes, int n_in,
                              void* d_out, int out_size, void* d_ws, size_t ws_size,
                              hipStream_t stream) {
    const float* x      = (const float*)d_in[0];
    const float* W_attn = (const float*)d_in[1];
    const float* W_proj = (const float*)d_in[2];
    float* out = (float*)d_out;

    char* ws = (char*)d_ws;
    bf16* xb   = (bf16*)(ws);                  //  4096x1024 bf16 =  8 MiB
    bf16* WaT  = (bf16*)(ws + 8388608);        //  3072x1024 bf16 =  6 MiB
    bf16* WpT  = (bf16*)(ws + 14680064);       //  1024x1024 bf16 =  2 MiB
    bf16* qkv  = (bf16*)(ws + 16777216);       //  4096x3072 bf16 = 24 MiB
    bf16* yatt = (bf16*)(ws + 41943040);       //  4096x1024 bf16 =  8 MiB

    cast_f32_bf16_kernel<<<4096, 256, 0, stream>>>(x, xb, 1048576);
    transpose_cast_kernel<<<dim3(48, 16), 256, 0, stream>>>(W_attn, WaT, 1024, 3072);
    transpose_cast_kernel<<<dim3(16, 16), 256, 0, stream>>>(W_proj, WpT, 1024, 1024);

    gemm256_kernel<<<192, 512, 0, stream>>>(xb, WaT, qkv, 4096, 3072, 1024);
    attn_kernel<<<1024, 256, 0, stream>>>(qkv, yatt);
    gemm_bt_kernel<false><<<dim3(8, 32), 256, 0, stream>>>(yatt, WpT, nullptr, out, 4096, 1024, 1024);
}

// Round 5
// 111.168 us; speedup vs baseline: 1.2369x; 1.0074x over previous
//
#include <hip/hip_runtime.h>

typedef __bf16 bf16;
typedef __bf16 bf16x4 __attribute__((ext_vector_type(4)));
typedef __bf16 bf16x8 __attribute__((ext_vector_type(8)));
typedef float f32x4 __attribute__((ext_vector_type(4)));

#define T_SEQ 2048
#define CDIM  1024
#define QKV_LD 3072
#define MEM   256

// global -> LDS direct DMA, 16B per lane. LDS dest is wave-uniform base + lane*16B.
#define GLOAD_LDS16(gp, lp) __builtin_amdgcn_global_load_lds( \
    (const __attribute__((address_space(1))) unsigned int*)(gp), \
    (__attribute__((address_space(3))) unsigned int*)(lp), 16, 0, 0)

#define BAR() do { __builtin_amdgcn_s_barrier(); asm volatile("" ::: "memory"); } while (0)

// ---------------- cast f32 -> bf16 (vectorized x4) ----------------
__global__ __launch_bounds__(256) void cast_f32_bf16_kernel(const float* __restrict__ in,
                                                            bf16* __restrict__ out, int n4) {
    int i = blockIdx.x * 256 + threadIdx.x;
    if (i < n4) {
        float4 v = reinterpret_cast<const float4*>(in)[i];
        bf16x4 o = { (bf16)v.x, (bf16)v.y, (bf16)v.z, (bf16)v.w };
        reinterpret_cast<bf16x4*>(out)[i] = o;
    }
}

// ------------- transpose+cast: W[K][N] f32 -> Wt[N][K] bf16 -------------
__global__ __launch_bounds__(256) void transpose_cast_kernel(const float* __restrict__ W,
                                                             bf16* __restrict__ Wt,
                                                             int K, int N) {
    __shared__ float tile[64][65];
    const int n0 = blockIdx.x * 64;
    const int k0 = blockIdx.y * 64;
    const int t  = threadIdx.x;
    const int tr = t >> 4;
    const int tc = (t & 15) * 4;
#pragma unroll
    for (int it = 0; it < 4; ++it) {
        int r = it * 16 + tr;
        float4 v = *reinterpret_cast<const float4*>(&W[(size_t)(k0 + r) * N + n0 + tc]);
        tile[r][tc + 0] = v.x; tile[r][tc + 1] = v.y;
        tile[r][tc + 2] = v.z; tile[r][tc + 3] = v.w;
    }
    __syncthreads();
#pragma unroll
    for (int it = 0; it < 4; ++it) {
        int n = it * 16 + tr;
        bf16x4 o;
#pragma unroll
        for (int j = 0; j < 4; ++j) o[j] = (bf16)tile[tc + j][n];
        *reinterpret_cast<bf16x4*>(&Wt[(size_t)(n0 + n) * K + k0 + tc]) = o;
    }
}

// ------------- 256x256 GEMM, fine-interleaved pipeline: C = A[M][K] * Bt[N][K]^T -------------
// 512 thr = 8 waves (2M x 4N); per-wave C = 128x64. BK=64, dbuf LDS, counted vmcnt(6).
// Per K-tile: issue 24 ds_reads in dep-ordered groups (12/8/4), 1 barrier, then 4 MFMA
// quadrants overlapping outstanding reads (in-order lgkm), stages interleaved between quads.
__global__ __launch_bounds__(512, 1) void gemm256_kernel(const bf16* __restrict__ A,
                                                         const bf16* __restrict__ Bt,
                                                         bf16* __restrict__ Cb,
                                                         int M, int N, int K) {
    __shared__ bf16 sm[2][2][256][64];   // [buf][mat A/B][row][k]
    const int t    = threadIdx.x;
    const int lane = t & 63;
    const int w    = t >> 6;
    const int wm   = (w >> 2) * 128;     // wave row-half
    const int wn   = (w & 3) * 64;       // wave col-quarter
    const int g    = lane >> 4;
    const int r    = lane & 15;

    const int nwg = gridDim.x, cpx = nwg >> 3;
    const int swz = (blockIdx.x & 7) * cpx + (blockIdx.x >> 3);
    const int ntn = N >> 8;
    const int m0 = (swz / ntn) * 256;
    const int n0 = (swz % ntn) * 256;

    const bf16* Ab = A  + (size_t)m0 * K;
    const bf16* Bb = Bt + (size_t)n0 * K;
    const int NT = K >> 6;               // K-tiles of 64

#define STAGE(bi, mat, half, kt, gbase) do { \
    _Pragma("unroll") \
    for (int ii = 0; ii < 2; ++ii) { \
        const bf16* _s = (gbase) + (size_t)((half) * 128 + ii * 64 + w * 8 + (lane >> 3)) * K \
                         + (kt) * 64 + ((lane & 7) ^ (lane >> 3)) * 8; \
        GLOAD_LDS16(_s, &sm[bi][mat][(half) * 128 + ii * 64 + w * 8][0]); \
    } } while (0)

    const int ch0 = ((g     ) ^ (r & 7)) * 8;
    const int ch1 = ((g ^ 4) ^ (r & 7)) * 8;

    const f32x4 zero4 = {0.f, 0.f, 0.f, 0.f};
    f32x4 acc[8][4];
#pragma unroll
    for (int i = 0; i < 8; ++i)
#pragma unroll
        for (int j = 0; j < 4; ++j) acc[i][j] = zero4;

    bf16x8 afr0[4][2], afr1[4][2], bfrA[2][2], bfrB[2][2];

    // one MFMA quadrant: 4 fm x 2 fn x 2 kh = 16 MFMA
#define MQUAD(AF, FMB, BF, FNB) do { \
    __builtin_amdgcn_s_setprio(1); \
    _Pragma("unroll") \
    for (int fm2 = 0; fm2 < 4; ++fm2) \
    _Pragma("unroll") \
    for (int fn2 = 0; fn2 < 2; ++fn2) \
    _Pragma("unroll") \
    for (int kh = 0; kh < 2; ++kh) \
        acc[(FMB)+fm2][(FNB)+fn2] = __builtin_amdgcn_mfma_f32_16x16x32_bf16( \
            AF[fm2][kh], BF[fn2][kh], acc[(FMB)+fm2][(FNB)+fn2], 0, 0, 0); \
    __builtin_amdgcn_s_setprio(0); } while (0)

    // ---- prologue: T0 fully + T1 {A-h0, A-h1, B-h0}; wait T0 landed ----
    STAGE(0, 0, 0, 0, Ab); STAGE(0, 0, 1, 0, Ab);
    STAGE(0, 1, 0, 0, Bb); STAGE(0, 1, 1, 0, Bb);
    if (NT > 1) { STAGE(1, 0, 0, 1, Ab); STAGE(1, 0, 1, 1, Ab); STAGE(1, 1, 0, 1, Bb); }
    if (NT > 1) { asm volatile("s_waitcnt vmcnt(6)" ::: "memory"); }
    else        { asm volatile("s_waitcnt vmcnt(0)" ::: "memory"); }
    __builtin_amdgcn_sched_barrier(0);
    BAR();

    for (int kt = 0; kt < NT; ++kt) {
        const int cur = kt & 1, nxt = cur ^ 1;
        // ---- R0 (12 reads): afr0 + bfrA — feeds quadrant M0 ----
#pragma unroll
        for (int i = 0; i < 4; ++i) {
            afr0[i][0] = *reinterpret_cast<const bf16x8*>(&sm[cur][0][wm + i * 16 + r][ch0]);
            afr0[i][1] = *reinterpret_cast<const bf16x8*>(&sm[cur][0][wm + i * 16 + r][ch1]);
        }
#pragma unroll
        for (int fn = 0; fn < 2; ++fn) {
            bfrA[fn][0] = *reinterpret_cast<const bf16x8*>(&sm[cur][1][wn + fn * 16 + r][ch0]);
            bfrA[fn][1] = *reinterpret_cast<const bf16x8*>(&sm[cur][1][wn + fn * 16 + r][ch1]);
        }
        // ---- R1 (8 reads): afr1 — feeds M1 ----
#pragma unroll
        for (int i = 0; i < 4; ++i) {
            afr1[i][0] = *reinterpret_cast<const bf16x8*>(&sm[cur][0][wm + 64 + i * 16 + r][ch0]);
            afr1[i][1] = *reinterpret_cast<const bf16x8*>(&sm[cur][0][wm + 64 + i * 16 + r][ch1]);
        }
        // ---- R2 (4 reads): bfrB — feeds M2/M3 ----
#pragma unroll
        for (int fn = 0; fn < 2; ++fn) {
            bfrB[fn][0] = *reinterpret_cast<const bf16x8*>(&sm[cur][1][wn + 32 + fn * 16 + r][ch0]);
            bfrB[fn][1] = *reinterpret_cast<const bf16x8*>(&sm[cur][1][wn + 32 + fn * 16 + r][ch1]);
        }
        if (kt + 1 < NT) STAGE(nxt, 1, 1, kt + 1, Bb);
        __builtin_amdgcn_sched_barrier(0);   // pin: all reads + stage issued before barrier
        BAR();                                // all waves' reads of buf[cur] issued

        // ---- 4 quadrants; each overlaps later quadrants' outstanding reads; stages interleaved ----
        MQUAD(afr0, 0, bfrA, 0);              // waits R0 only (12), leaves 12 in flight
        if (kt + 2 < NT) STAGE(cur, 0, 0, kt + 2, Ab);
        MQUAD(afr1, 4, bfrA, 0);              // waits R1
        if (kt + 2 < NT) STAGE(cur, 0, 1, kt + 2, Ab);
        MQUAD(afr1, 4, bfrB, 2);              // waits R2
        if (kt + 2 < NT) STAGE(cur, 1, 0, kt + 2, Bb);
        MQUAD(afr0, 0, bfrB, 2);              // no wait

        if (kt == NT - 2)      { asm volatile("s_waitcnt vmcnt(0)" ::: "memory"); }
        else if (kt < NT - 2)  { asm volatile("s_waitcnt vmcnt(6)" ::: "memory"); }
        __builtin_amdgcn_sched_barrier(0);
        BAR();                                // buf[cur ^ 1] (= next tile) landed; safe to read
    }

    // ---- epilogue: C/D layout col = lane&15, row = 4*(lane>>4)+e ----
#pragma unroll
    for (int fm = 0; fm < 8; ++fm)
#pragma unroll
        for (int fn = 0; fn < 4; ++fn)
#pragma unroll
            for (int e = 0; e < 4; ++e) {
                int row = m0 + wm + fm * 16 + g * 4 + e;
                int col = n0 + wn + fn * 16 + r;
                Cb[(size_t)row * N + col] = (bf16)acc[fm][fn][e];
            }
#undef STAGE
#undef MQUAD
}

// ------------- GEMM: C[M][N] = A[M][K] * Bt[N][K]^T  (m97 structure, proj) -------------
template<bool OUT_BF16>
__global__ __launch_bounds__(256) void gemm_bt_kernel(const bf16* __restrict__ A,
                                                      const bf16* __restrict__ Bt,
                                                      bf16* __restrict__ Cb,
                                                      float* __restrict__ Cf,
                                                      int M, int N, int K) {
    __shared__ bf16 As[128 * 32];
    __shared__ bf16 Bs[128 * 32];
    const int t    = threadIdx.x;
    const int lane = t & 63;
    const int w    = t >> 6;
    const int wm   = (w >> 1) * 64;
    const int wn   = (w & 1) * 64;
    const int g    = lane >> 4;
    const int r    = lane & 15;
    const int m0   = blockIdx.y * 128;
    const int n0   = blockIdx.x * 128;

    const bf16* Ab = A  + (size_t)m0 * K;
    const bf16* Bb = Bt + (size_t)n0 * K;
    const bf16* Ag0 = Ab + (size_t)(w * 32 + (lane >> 2)) * K + (lane & 3) * 8;
    const bf16* Ag1 = Ab + (size_t)(w * 32 + 16 + (lane >> 2)) * K + (lane & 3) * 8;
    const bf16* Bg0 = Bb + (size_t)(w * 32 + (lane >> 2)) * K + (lane & 3) * 8;
    const bf16* Bg1 = Bb + (size_t)(w * 32 + 16 + (lane >> 2)) * K + (lane & 3) * 8;

    bf16* ldsA0 = As + (w * 32) * 32;
    bf16* ldsA1 = As + (w * 32 + 16) * 32;
    bf16* ldsB0 = Bs + (w * 32) * 32;
    bf16* ldsB1 = Bs + (w * 32 + 16) * 32;

    const f32x4 zero4 = {0.f, 0.f, 0.f, 0.f};
    f32x4 acc[4][4];
#pragma unroll
    for (int i = 0; i < 4; ++i)
#pragma unroll
        for (int j = 0; j < 4; ++j) acc[i][j] = zero4;

    for (int k0 = 0; k0 < K; k0 += 32) {
        __syncthreads();
        GLOAD_LDS16(Ag0 + k0, ldsA0);
        GLOAD_LDS16(Ag1 + k0, ldsA1);
        GLOAD_LDS16(Bg0 + k0, ldsB0);
        GLOAD_LDS16(Bg1 + k0, ldsB1);
        __syncthreads();

        bf16x8 af[4], bfr[4];
#pragma unroll
        for (int i = 0; i < 4; ++i) {
            af[i]  = *reinterpret_cast<const bf16x8*>(&As[(wm + i * 16 + r) * 32 + g * 8]);
            bfr[i] = *reinterpret_cast<const bf16x8*>(&Bs[(wn + i * 16 + r) * 32 + g * 8]);
        }
#pragma unroll
        for (int i = 0; i < 4; ++i)
#pragma unroll
            for (int j = 0; j < 4; ++j)
                acc[i][j] = __builtin_amdgcn_mfma_f32_16x16x32_bf16(af[i], bfr[j], acc[i][j], 0, 0, 0);
    }

#pragma unroll
    for (int i = 0; i < 4; ++i)
#pragma unroll
        for (int j = 0; j < 4; ++j)
#pragma unroll
            for (int e = 0; e < 4; ++e) {
                int row = m0 + wm + i * 16 + g * 4 + e;
                int col = n0 + wn + j * 16 + r;
                if constexpr (OUT_BF16) Cb[(size_t)row * N + col] = (bf16)acc[i][j][e];
                else                    Cf[(size_t)row * N + col] = acc[i][j][e];
            }
}

// ------------- banded flash attention v3: block-level V^T LDS staging -------------
__global__ __launch_bounds__(256) void attn_kernel(const bf16* __restrict__ qkv,
                                                   bf16* __restrict__ y) {
    __shared__ bf16 vt[64][388];         // [d][krel], pad 388 (=4*97) vs 384 window
    const int bid  = blockIdx.x;
    const int bh   = bid >> 5;
    const int qblk = bid & 31;
    const int b = bh >> 4, h = bh & 15;
    const int qb0 = qblk * 64;
    const int wlo = qb0 - 256;           // window start (may be negative)
    const int w    = threadIdx.x >> 6;
    const int lane = threadIdx.x & 63;
    const int g = lane >> 4, c = lane & 15;
    const int q0 = qb0 + w * 16;
    const int q = q0 + c;
    const float NEG_INF = -__builtin_inff();

    const bf16* base = qkv + (size_t)b * T_SEQ * QKV_LD;
    const bf16* Qb = base + h * 64;
    const bf16* Kb = base + CDIM + h * 64;
    const bf16* Vb = base + 2 * CDIM + h * 64;

    // ---- stage V^T: rows [wlo, wlo+384) of V -> vt[d][krel] (edge rows clamped; masked anyway)
#pragma unroll
    for (int it = 0; it < 12; ++it) {
        int idx = it * 256 + threadIdx.x;   // 0..3071 = 384 rows x 8 chunks
        int row = idx >> 3, ch = idx & 7;
        int gk = wlo + row;
        gk = gk < 0 ? 0 : (gk > T_SEQ - 1 ? T_SEQ - 1 : gk);
        bf16x8 v = *reinterpret_cast<const bf16x8*>(Vb + (size_t)gk * QKV_LD + ch * 8);
#pragma unroll
        for (int j = 0; j < 8; ++j) vt[ch * 8 + j][row] = v[j];
    }

    const bf16x8 qf0 = *reinterpret_cast<const bf16x8*>(Qb + (size_t)q * QKV_LD + g * 8);
    const bf16x8 qf1 = *reinterpret_cast<const bf16x8*>(Qb + (size_t)q * QKV_LD + 32 + g * 8);

    __syncthreads();

    const f32x4 zero4 = {0.f, 0.f, 0.f, 0.f};
    f32x4 o[4];
#pragma unroll
    for (int cb = 0; cb < 4; ++cb) o[cb] = zero4;
    float m_run = NEG_INF, l_run = 0.f;

    const int jstart = (q0 - MEM > 0) ? (q0 - MEM) : 0;
    for (int j0 = jstart; j0 < q0 + 16; j0 += 32) {
        // --- S^T = mfma(K, Q) for 32 keys ---
        const int kr0 = j0 + c;
        int kr1 = j0 + 16 + c; kr1 = kr1 < T_SEQ ? kr1 : T_SEQ - 1;
        bf16x8 kf00 = *reinterpret_cast<const bf16x8*>(Kb + (size_t)kr0 * QKV_LD + g * 8);
        bf16x8 kf01 = *reinterpret_cast<const bf16x8*>(Kb + (size_t)kr0 * QKV_LD + 32 + g * 8);
        bf16x8 kf10 = *reinterpret_cast<const bf16x8*>(Kb + (size_t)kr1 * QKV_LD + g * 8);
        bf16x8 kf11 = *reinterpret_cast<const bf16x8*>(Kb + (size_t)kr1 * QKV_LD + 32 + g * 8);
        f32x4 s0 = __builtin_amdgcn_mfma_f32_16x16x32_bf16(kf00, qf0, zero4, 0, 0, 0);
        s0 = __builtin_amdgcn_mfma_f32_16x16x32_bf16(kf01, qf1, s0, 0, 0, 0);
        f32x4 s1 = __builtin_amdgcn_mfma_f32_16x16x32_bf16(kf10, qf0, zero4, 0, 0, 0);
        s1 = __builtin_amdgcn_mfma_f32_16x16x32_bf16(kf11, qf1, s1, 0, 0, 0);

        // --- scale + band mask; S^T value (lane,e) = S[key=j0+4g+e(+16)][q=c] ---
        float mt = NEG_INF;
#pragma unroll
        for (int e = 0; e < 4; ++e) {
            int k0i = j0 + 4 * g + e;
            int k1i = k0i + 16;
            float v0 = (k0i <= q && k0i >= q - MEM) ? s0[e] * 0.125f : NEG_INF;
            float v1 = (k1i <= q && k1i >= q - MEM) ? s1[e] * 0.125f : NEG_INF;
            s0[e] = v0; s1[e] = v1;
            mt = fmaxf(mt, fmaxf(v0, v1));
        }
        mt = fmaxf(mt, __shfl_xor(mt, 16, 64));
        mt = fmaxf(mt, __shfl_xor(mt, 32, 64));
        const float mnew = fmaxf(m_run, mt);
        const float corr = __expf(m_run - mnew);

        float ps = 0.f;
        bf16x8 pav;
#pragma unroll
        for (int e = 0; e < 4; ++e) {
            float e0 = __expf(s0[e] - mnew);
            float e1 = __expf(s1[e] - mnew);
            ps += e0 + e1;
            pav[e]     = (bf16)e0;
            pav[4 + e] = (bf16)e1;
        }
        ps += __shfl_xor(ps, 16, 64);
        ps += __shfl_xor(ps, 32, 64);
        l_run = l_run * corr + ps;
        m_run = mnew;

        // --- O^T rescale: lane-local (q = c for all regs) ---
#pragma unroll
        for (int cb = 0; cb < 4; ++cb) {
            o[cb][0] *= corr; o[cb][1] *= corr; o[cb][2] *= corr; o[cb][3] *= corr;
        }

        // --- PV as O^T = mfma(V-frag, pav): vf[jj] = V[j0+kmap(g,jj)][cb*16+c] ---
        const int jrel = j0 - wlo;
#pragma unroll
        for (int cb = 0; cb < 4; ++cb) {
            const bf16* vr = &vt[cb * 16 + c][jrel + 4 * g];
            bf16x4 va  = *reinterpret_cast<const bf16x4*>(vr);
            bf16x4 vb2 = *reinterpret_cast<const bf16x4*>(vr + 16);
            bf16x8 vf = { va[0], va[1], va[2], va[3], vb2[0], vb2[1], vb2[2], vb2[3] };
            o[cb] = __builtin_amdgcn_mfma_f32_16x16x32_bf16(vf, pav, o[cb], 0, 0, 0);
        }
    }

    // --- epilogue: o[cb][e] = O[q=q0+c][d = cb*16+4g+e]; lane-local divide; bf16x4 stores ---
    const float linv = 1.0f / l_run;
    bf16* yr = y + (size_t)(b * T_SEQ + q) * CDIM + h * 64 + 4 * g;
#pragma unroll
    for (int cb = 0; cb < 4; ++cb) {
        bf16x4 ov = { (bf16)(o[cb][0] * linv), (bf16)(o[cb][1] * linv),
                      (bf16)(o[cb][2] * linv), (bf16)(o[cb][3] * linv) };
        *reinterpret_cast<bf16x4*>(yr + cb * 16) = ov;
    }
}

// ---------------- launch ----------------
extern "C" void kernel_launch(void* const* d_in, const int* in_sizes, int n_in,
                              void* d_out, int out_size, void* d_ws, size_t ws_size,
                              hipStream_t stream) {
    const float* x      = (const float*)d_in[0];
    const float* W_attn = (const float*)d_in[1];
    const float* W_proj = (const float*)d_in[2];
    float* out = (float*)d_out;

    char* ws = (char*)d_ws;
    bf16* xb   = (bf16*)(ws);                  //  4096x1024 bf16 =  8 MiB
    bf16* WaT  = (bf16*)(ws + 8388608);        //  3072x1024 bf16 =  6 MiB
    bf16* WpT  = (bf16*)(ws + 14680064);       //  1024x1024 bf16 =  2 MiB
    bf16* qkv  = (bf16*)(ws + 16777216);       //  4096x3072 bf16 = 24 MiB
    bf16* yatt = (bf16*)(ws + 41943040);       //  4096x1024 bf16 =  8 MiB

    cast_f32_bf16_kernel<<<4096, 256, 0, stream>>>(x, xb, 1048576);
    transpose_cast_kernel<<<dim3(48, 16), 256, 0, stream>>>(W_attn, WaT, 1024, 3072);
    transpose_cast_kernel<<<dim3(16, 16), 256, 0, stream>>>(W_proj, WpT, 1024, 1024);

    gemm256_kernel<<<192, 512, 0, stream>>>(xb, WaT, qkv, 4096, 3072, 1024);
    attn_kernel<<<1024, 256, 0, stream>>>(qkv, yatt);
    gemm_bt_kernel<false><<<dim3(8, 32), 256, 0, stream>>>(yatt, WpT, nullptr, out, 4096, 1024, 1024);
}

// Round 7
// 109.169 us; speedup vs baseline: 1.2596x; 1.0183x over previous
//
#include <hip/hip_runtime.h>

typedef __bf16 bf16;
typedef __bf16 bf16x4 __attribute__((ext_vector_type(4)));
typedef __bf16 bf16x8 __attribute__((ext_vector_type(8)));
typedef float f32x4 __attribute__((ext_vector_type(4)));

#define T_SEQ 2048
#define CDIM  1024
#define QKV_LD 3072
#define MEM   256

// global -> LDS direct DMA, 16B per lane. LDS dest is wave-uniform base + lane*16B.
#define GLOAD_LDS16(gp, lp) __builtin_amdgcn_global_load_lds( \
    (const __attribute__((address_space(1))) unsigned int*)(gp), \
    (__attribute__((address_space(3))) unsigned int*)(lp), 16, 0, 0)

#define BAR() do { __builtin_amdgcn_s_barrier(); asm volatile("" ::: "memory"); } while (0)

// ---------------- cast f32 -> bf16 (vectorized x4) ----------------
__global__ __launch_bounds__(256) void cast_f32_bf16_kernel(const float* __restrict__ in,
                                                            bf16* __restrict__ out, int n4) {
    int i = blockIdx.x * 256 + threadIdx.x;
    if (i < n4) {
        float4 v = reinterpret_cast<const float4*>(in)[i];
        bf16x4 o = { (bf16)v.x, (bf16)v.y, (bf16)v.z, (bf16)v.w };
        reinterpret_cast<bf16x4*>(out)[i] = o;
    }
}

// ------------- transpose+cast: W[K][N] f32 -> Wt[N][K] bf16 -------------
__global__ __launch_bounds__(256) void transpose_cast_kernel(const float* __restrict__ W,
                                                             bf16* __restrict__ Wt,
                                                             int K, int N) {
    __shared__ float tile[64][65];
    const int n0 = blockIdx.x * 64;
    const int k0 = blockIdx.y * 64;
    const int t  = threadIdx.x;
    const int tr = t >> 4;
    const int tc = (t & 15) * 4;
#pragma unroll
    for (int it = 0; it < 4; ++it) {
        int r = it * 16 + tr;
        float4 v = *reinterpret_cast<const float4*>(&W[(size_t)(k0 + r) * N + n0 + tc]);
        tile[r][tc + 0] = v.x; tile[r][tc + 1] = v.y;
        tile[r][tc + 2] = v.z; tile[r][tc + 3] = v.w;
    }
    __syncthreads();
#pragma unroll
    for (int it = 0; it < 4; ++it) {
        int n = it * 16 + tr;
        bf16x4 o;
#pragma unroll
        for (int j = 0; j < 4; ++j) o[j] = (bf16)tile[tc + j][n];
        *reinterpret_cast<bf16x4*>(&Wt[(size_t)(n0 + n) * K + k0 + tc]) = o;
    }
}

// ------------- transpose V third of qkv: [T][64] per (b,h) -> Vt[b][h][64][T] -------------
__global__ __launch_bounds__(256) void transpose_v_kernel(const bf16* __restrict__ qkv,
                                                          bf16* __restrict__ Vt) {
    const int bid = blockIdx.x;
    const int tt = bid & 31, h = (bid >> 5) & 15, b = bid >> 9;
    __shared__ bf16 tile[64][72];
    const int i = threadIdx.x;
    {
        const int tr = i >> 2, dc = (i & 3) * 16;
        const bf16* src = qkv + (size_t)(b * T_SEQ + tt * 64 + tr) * QKV_LD + 2 * CDIM + h * 64 + dc;
        *reinterpret_cast<bf16x8*>(&tile[tr][dc])     = *reinterpret_cast<const bf16x8*>(src);
        *reinterpret_cast<bf16x8*>(&tile[tr][dc + 8]) = *reinterpret_cast<const bf16x8*>(src + 8);
    }
    __syncthreads();
    {
        const int dr = i >> 2, tc = (i & 3) * 16;
        bf16x8 o0, o1;
#pragma unroll
        for (int j = 0; j < 8; ++j) { o0[j] = tile[tc + j][dr]; o1[j] = tile[tc + 8 + j][dr]; }
        bf16* dst = Vt + ((size_t)((b * 16 + h) * 64 + dr)) * T_SEQ + tt * 64 + tc;
        *reinterpret_cast<bf16x8*>(dst)     = o0;
        *reinterpret_cast<bf16x8*>(dst + 8) = o1;
    }
}

// ------------- 256x256 GEMM, fine-interleaved pipeline (frozen from R5) -------------
__global__ __launch_bounds__(512, 1) void gemm256_kernel(const bf16* __restrict__ A,
                                                         const bf16* __restrict__ Bt,
                                                         bf16* __restrict__ Cb,
                                                         int M, int N, int K) {
    __shared__ bf16 sm[2][2][256][64];   // [buf][mat A/B][row][k]
    const int t    = threadIdx.x;
    const int lane = t & 63;
    const int w    = t >> 6;
    const int wm   = (w >> 2) * 128;
    const int wn   = (w & 3) * 64;
    const int g    = lane >> 4;
    const int r    = lane & 15;

    const int nwg = gridDim.x, cpx = nwg >> 3;
    const int swz = (blockIdx.x & 7) * cpx + (blockIdx.x >> 3);
    const int ntn = N >> 8;
    const int m0 = (swz / ntn) * 256;
    const int n0 = (swz % ntn) * 256;

    const bf16* Ab = A  + (size_t)m0 * K;
    const bf16* Bb = Bt + (size_t)n0 * K;
    const int NT = K >> 6;

#define STAGE(bi, mat, half, kt, gbase) do { \
    _Pragma("unroll") \
    for (int ii = 0; ii < 2; ++ii) { \
        const bf16* _s = (gbase) + (size_t)((half) * 128 + ii * 64 + w * 8 + (lane >> 3)) * K \
                         + (kt) * 64 + ((lane & 7) ^ (lane >> 3)) * 8; \
        GLOAD_LDS16(_s, &sm[bi][mat][(half) * 128 + ii * 64 + w * 8][0]); \
    } } while (0)

    const int ch0 = ((g     ) ^ (r & 7)) * 8;
    const int ch1 = ((g ^ 4) ^ (r & 7)) * 8;

    const f32x4 zero4 = {0.f, 0.f, 0.f, 0.f};
    f32x4 acc[8][4];
#pragma unroll
    for (int i = 0; i < 8; ++i)
#pragma unroll
        for (int j = 0; j < 4; ++j) acc[i][j] = zero4;

    bf16x8 afr0[4][2], afr1[4][2], bfrA[2][2], bfrB[2][2];

#define MQUAD(AF, FMB, BF, FNB) do { \
    __builtin_amdgcn_s_setprio(1); \
    _Pragma("unroll") \
    for (int fm2 = 0; fm2 < 4; ++fm2) \
    _Pragma("unroll") \
    for (int fn2 = 0; fn2 < 2; ++fn2) \
    _Pragma("unroll") \
    for (int kh = 0; kh < 2; ++kh) \
        acc[(FMB)+fm2][(FNB)+fn2] = __builtin_amdgcn_mfma_f32_16x16x32_bf16( \
            AF[fm2][kh], BF[fn2][kh], acc[(FMB)+fm2][(FNB)+fn2], 0, 0, 0); \
    __builtin_amdgcn_s_setprio(0); } while (0)

    STAGE(0, 0, 0, 0, Ab); STAGE(0, 0, 1, 0, Ab);
    STAGE(0, 1, 0, 0, Bb); STAGE(0, 1, 1, 0, Bb);
    if (NT > 1) { STAGE(1, 0, 0, 1, Ab); STAGE(1, 0, 1, 1, Ab); STAGE(1, 1, 0, 1, Bb); }
    if (NT > 1) { asm volatile("s_waitcnt vmcnt(6)" ::: "memory"); }
    else        { asm volatile("s_waitcnt vmcnt(0)" ::: "memory"); }
    __builtin_amdgcn_sched_barrier(0);
    BAR();

    for (int kt = 0; kt < NT; ++kt) {
        const int cur = kt & 1, nxt = cur ^ 1;
#pragma unroll
        for (int i = 0; i < 4; ++i) {
            afr0[i][0] = *reinterpret_cast<const bf16x8*>(&sm[cur][0][wm + i * 16 + r][ch0]);
            afr0[i][1] = *reinterpret_cast<const bf16x8*>(&sm[cur][0][wm + i * 16 + r][ch1]);
        }
#pragma unroll
        for (int fn = 0; fn < 2; ++fn) {
            bfrA[fn][0] = *reinterpret_cast<const bf16x8*>(&sm[cur][1][wn + fn * 16 + r][ch0]);
            bfrA[fn][1] = *reinterpret_cast<const bf16x8*>(&sm[cur][1][wn + fn * 16 + r][ch1]);
        }
#pragma unroll
        for (int i = 0; i < 4; ++i) {
            afr1[i][0] = *reinterpret_cast<const bf16x8*>(&sm[cur][0][wm + 64 + i * 16 + r][ch0]);
            afr1[i][1] = *reinterpret_cast<const bf16x8*>(&sm[cur][0][wm + 64 + i * 16 + r][ch1]);
        }
#pragma unroll
        for (int fn = 0; fn < 2; ++fn) {
            bfrB[fn][0] = *reinterpret_cast<const bf16x8*>(&sm[cur][1][wn + 32 + fn * 16 + r][ch0]);
            bfrB[fn][1] = *reinterpret_cast<const bf16x8*>(&sm[cur][1][wn + 32 + fn * 16 + r][ch1]);
        }
        if (kt + 1 < NT) STAGE(nxt, 1, 1, kt + 1, Bb);
        __builtin_amdgcn_sched_barrier(0);
        BAR();

        MQUAD(afr0, 0, bfrA, 0);
        if (kt + 2 < NT) STAGE(cur, 0, 0, kt + 2, Ab);
        MQUAD(afr1, 4, bfrA, 0);
        if (kt + 2 < NT) STAGE(cur, 0, 1, kt + 2, Ab);
        MQUAD(afr1, 4, bfrB, 2);
        if (kt + 2 < NT) STAGE(cur, 1, 0, kt + 2, Bb);
        MQUAD(afr0, 0, bfrB, 2);

        if (kt == NT - 2)      { asm volatile("s_waitcnt vmcnt(0)" ::: "memory"); }
        else if (kt < NT - 2)  { asm volatile("s_waitcnt vmcnt(6)" ::: "memory"); }
        __builtin_amdgcn_sched_barrier(0);
        BAR();
    }

#pragma unroll
    for (int fm = 0; fm < 8; ++fm)
#pragma unroll
        for (int fn = 0; fn < 4; ++fn)
#pragma unroll
            for (int e = 0; e < 4; ++e) {
                int row = m0 + wm + fm * 16 + g * 4 + e;
                int col = n0 + wn + fn * 16 + r;
                Cb[(size_t)row * N + col] = (bf16)acc[fm][fn][e];
            }
#undef STAGE
#undef MQUAD
}

// ------------- GEMM: C[M][N] = A[M][K] * Bt[N][K]^T  (m97 structure, proj; frozen) -------------
template<bool OUT_BF16>
__global__ __launch_bounds__(256) void gemm_bt_kernel(const bf16* __restrict__ A,
                                                      const bf16* __restrict__ Bt,
                                                      bf16* __restrict__ Cb,
                                                      float* __restrict__ Cf,
                                                      int M, int N, int K) {
    __shared__ bf16 As[128 * 32];
    __shared__ bf16 Bs[128 * 32];
    const int t    = threadIdx.x;
    const int lane = t & 63;
    const int w    = t >> 6;
    const int wm   = (w >> 1) * 64;
    const int wn   = (w & 1) * 64;
    const int g    = lane >> 4;
    const int r    = lane & 15;
    const int m0   = blockIdx.y * 128;
    const int n0   = blockIdx.x * 128;

    const bf16* Ab = A  + (size_t)m0 * K;
    const bf16* Bb = Bt + (size_t)n0 * K;
    const bf16* Ag0 = Ab + (size_t)(w * 32 + (lane >> 2)) * K + (lane & 3) * 8;
    const bf16* Ag1 = Ab + (size_t)(w * 32 + 16 + (lane >> 2)) * K + (lane & 3) * 8;
    const bf16* Bg0 = Bb + (size_t)(w * 32 + (lane >> 2)) * K + (lane & 3) * 8;
    const bf16* Bg1 = Bb + (size_t)(w * 32 + 16 + (lane >> 2)) * K + (lane & 3) * 8;

    bf16* ldsA0 = As + (w * 32) * 32;
    bf16* ldsA1 = As + (w * 32 + 16) * 32;
    bf16* ldsB0 = Bs + (w * 32) * 32;
    bf16* ldsB1 = Bs + (w * 32 + 16) * 32;

    const f32x4 zero4 = {0.f, 0.f, 0.f, 0.f};
    f32x4 acc[4][4];
#pragma unroll
    for (int i = 0; i < 4; ++i)
#pragma unroll
        for (int j = 0; j < 4; ++j) acc[i][j] = zero4;

    for (int k0 = 0; k0 < K; k0 += 32) {
        __syncthreads();
        GLOAD_LDS16(Ag0 + k0, ldsA0);
        GLOAD_LDS16(Ag1 + k0, ldsA1);
        GLOAD_LDS16(Bg0 + k0, ldsB0);
        GLOAD_LDS16(Bg1 + k0, ldsB1);
        __syncthreads();

        bf16x8 af[4], bfr[4];
#pragma unroll
        for (int i = 0; i < 4; ++i) {
            af[i]  = *reinterpret_cast<const bf16x8*>(&As[(wm + i * 16 + r) * 32 + g * 8]);
            bfr[i] = *reinterpret_cast<const bf16x8*>(&Bs[(wn + i * 16 + r) * 32 + g * 8]);
        }
#pragma unroll
        for (int i = 0; i < 4; ++i)
#pragma unroll
            for (int j = 0; j < 4; ++j)
                acc[i][j] = __builtin_amdgcn_mfma_f32_16x16x32_bf16(af[i], bfr[j], acc[i][j], 0, 0, 0);
    }

#pragma unroll
    for (int i = 0; i < 4; ++i)
#pragma unroll
        for (int j = 0; j < 4; ++j)
#pragma unroll
            for (int e = 0; e < 4; ++e) {
                int row = m0 + wm + i * 16 + g * 4 + e;
                int col = n0 + wn + j * 16 + r;
                if constexpr (OUT_BF16) Cb[(size_t)row * N + col] = (bf16)acc[i][j][e];
                else                    Cf[(size_t)row * N + col] = acc[i][j][e];
            }
}

// ------------- banded flash attention v4.1: 128-row blocks, linear gload V^T staging -------------
// Fix vs v4: the last K-tile's second subtile (keys >= qb0+128) lies outside the staged
// 384-element window ONLY when those keys are fully masked -> clamp the read chunk in-bounds
// (garbage * P=0 = 0). Chunk set 0..95 is closed under the XOR swizzle (x<=14 flips bits 1-3).
__global__ __launch_bounds__(512) void attn_kernel(const bf16* __restrict__ qkv,
                                                   const bf16* __restrict__ Vt,
                                                   bf16* __restrict__ y) {
    __shared__ bf16 vtl[64 * 384];       // linear, no pad; swizzle via source/read XOR
    const int bid  = blockIdx.x;
    const int bh   = bid >> 4;
    const int qblk = bid & 15;
    const int b = bh >> 4, h = bh & 15;
    const int qb0 = qblk * 128;
    const int wlo = qb0 - 256;           // window start (may be negative)
    const int wv   = threadIdx.x >> 6;   // wave 0..7
    const int lane = threadIdx.x & 63;
    const int g = lane >> 4, c = lane & 15;
    const int q0 = qb0 + wv * 16;
    const int q = q0 + c;
    const float NEG_INF = -__builtin_inff();

    const bf16* base = qkv + (size_t)b * T_SEQ * QKV_LD;
    const bf16* Qb = base + h * 64;
    const bf16* Kb = base + CDIM + h * 64;
    const bf16* Vtb = Vt + (size_t)(b * 16 + h) * 64 * T_SEQ;

    // ---- stage V^T window: 48KB linear, 6 gload issues/wave; source pre-swizzled (x = d&14)
#pragma unroll
    for (int i = 0; i < 6; ++i) {
        const int Lb = (wv * 6 + i) * 1024 + lane * 16;  // linear LDS byte this lane covers
        const int d   = Lb / 768;
        const int c16 = (Lb % 768) >> 4;                 // 16B-pair index within row
        int koff = ((2 * c16) ^ (d & 14)) << 2;          // logical elem offset of this 16B
        int gk = wlo + koff;
        gk = gk < 0 ? 0 : gk;                            // clamp (region masked in compute)
        GLOAD_LDS16(Vtb + (size_t)d * T_SEQ + gk, vtl + (wv * 6 + i) * 512);
    }

    const bf16x8 qf0 = *reinterpret_cast<const bf16x8*>(Qb + (size_t)q * QKV_LD + g * 8);
    const bf16x8 qf1 = *reinterpret_cast<const bf16x8*>(Qb + (size_t)q * QKV_LD + 32 + g * 8);

    __syncthreads();

    const f32x4 zero4 = {0.f, 0.f, 0.f, 0.f};
    f32x4 o[4];
#pragma unroll
    for (int cb = 0; cb < 4; ++cb) o[cb] = zero4;
    float m_run = NEG_INF, l_run = 0.f;

    const int jstart = (q0 - MEM > 0) ? (q0 - MEM) : 0;
    for (int j0 = jstart; j0 < q0 + 16; j0 += 32) {
        // --- S^T = mfma(K, Q) for 32 keys ---
        const int kr0 = j0 + c;
        int kr1 = j0 + 16 + c; kr1 = kr1 < T_SEQ ? kr1 : T_SEQ - 1;
        bf16x8 kf00 = *reinterpret_cast<const bf16x8*>(Kb + (size_t)kr0 * QKV_LD + g * 8);
        bf16x8 kf01 = *reinterpret_cast<const bf16x8*>(Kb + (size_t)kr0 * QKV_LD + 32 + g * 8);
        bf16x8 kf10 = *reinterpret_cast<const bf16x8*>(Kb + (size_t)kr1 * QKV_LD + g * 8);
        bf16x8 kf11 = *reinterpret_cast<const bf16x8*>(Kb + (size_t)kr1 * QKV_LD + 32 + g * 8);
        f32x4 s0 = __builtin_amdgcn_mfma_f32_16x16x32_bf16(kf00, qf0, zero4, 0, 0, 0);
        s0 = __builtin_amdgcn_mfma_f32_16x16x32_bf16(kf01, qf1, s0, 0, 0, 0);
        f32x4 s1 = __builtin_amdgcn_mfma_f32_16x16x32_bf16(kf10, qf0, zero4, 0, 0, 0);
        s1 = __builtin_amdgcn_mfma_f32_16x16x32_bf16(kf11, qf1, s1, 0, 0, 0);

        // --- scale + band mask; S^T value (lane,e) = S[key=j0+4g+e(+16)][q=c] ---
        float mt = NEG_INF;
#pragma unroll
        for (int e = 0; e < 4; ++e) {
            int k0i = j0 + 4 * g + e;
            int k1i = k0i + 16;
            float v0 = (k0i <= q && k0i >= q - MEM) ? s0[e] * 0.125f : NEG_INF;
            float v1 = (k1i <= q && k1i >= q - MEM) ? s1[e] * 0.125f : NEG_INF;
            s0[e] = v0; s1[e] = v1;
            mt = fmaxf(mt, fmaxf(v0, v1));
        }
        mt = fmaxf(mt, __shfl_xor(mt, 16, 64));
        mt = fmaxf(mt, __shfl_xor(mt, 32, 64));
        const float mnew = fmaxf(m_run, mt);
        const float corr = __expf(m_run - mnew);

        float ps = 0.f;
        bf16x8 pav;
#pragma unroll
        for (int e = 0; e < 4; ++e) {
            float e0 = __expf(s0[e] - mnew);
            float e1 = __expf(s1[e] - mnew);
            ps += e0 + e1;
            pav[e]     = (bf16)e0;
            pav[4 + e] = (bf16)e1;
        }
        ps += __shfl_xor(ps, 16, 64);
        ps += __shfl_xor(ps, 32, 64);
        l_run = l_run * corr + ps;
        m_run = mnew;

        // --- O^T rescale: lane-local (q = c for all regs) ---
#pragma unroll
        for (int cb = 0; cb < 4; ++cb) {
            o[cb][0] *= corr; o[cb][1] *= corr; o[cb][2] *= corr; o[cb][3] *= corr;
        }

        // --- PV as O^T = mfma(V-frag, pav); V-frag via swizzled ds_read_b64 x2 ---
        const int jrel = j0 - wlo;
        const int c8a = (jrel + 4 * g) >> 2;       // 8B-chunk index (always 4-elem aligned)
        const int c8b = (c8a + 4 > 95) ? 95 : (c8a + 4);  // overrun => keys fully masked (P=0)
#pragma unroll
        for (int cb = 0; cb < 4; ++cb) {
            const int d = cb * 16 + c;
            const int xx = d & 14;
            const bf16* vrow = vtl + d * 384;
            bf16x4 va  = *reinterpret_cast<const bf16x4*>(vrow + ((c8a ^ xx) << 2));
            bf16x4 vb2 = *reinterpret_cast<const bf16x4*>(vrow + ((c8b ^ xx) << 2));
            bf16x8 vf = { va[0], va[1], va[2], va[3], vb2[0], vb2[1], vb2[2], vb2[3] };
            o[cb] = __builtin_amdgcn_mfma_f32_16x16x32_bf16(vf, pav, o[cb], 0, 0, 0);
        }
    }

    // --- epilogue: o[cb][e] = O[q=q0+c][d = cb*16+4g+e]; lane-local divide; bf16x4 stores ---
    const float linv = 1.0f / l_run;
    bf16* yr = y + (size_t)(b * T_SEQ + q) * CDIM + h * 64 + 4 * g;
#pragma unroll
    for (int cb = 0; cb < 4; ++cb) {
        bf16x4 ov = { (bf16)(o[cb][0] * linv), (bf16)(o[cb][1] * linv),
                      (bf16)(o[cb][2] * linv), (bf16)(o[cb][3] * linv) };
        *reinterpret_cast<bf16x4*>(yr + cb * 16) = ov;
    }
}

// ---------------- launch ----------------
extern "C" void kernel_launch(void* const* d_in, const int* in_sizes, int n_in,
                              void* d_out, int out_size, void* d_ws, size_t ws_size,
                              hipStream_t stream) {
    const float* x      = (const float*)d_in[0];
    const float* W_attn = (const float*)d_in[1];
    const float* W_proj = (const float*)d_in[2];
    float* out = (float*)d_out;

    char* ws = (char*)d_ws;
    bf16* xb   = (bf16*)(ws);                  //  4096x1024 bf16 =  8 MiB (dead after gemm256)
    bf16* WaT  = (bf16*)(ws + 8388608);        //  3072x1024 bf16 =  6 MiB
    bf16* WpT  = (bf16*)(ws + 14680064);       //  1024x1024 bf16 =  2 MiB
    bf16* qkv  = (bf16*)(ws + 16777216);       //  4096x3072 bf16 = 24 MiB
    bf16* yatt = (bf16*)(ws + 41943040);       //  4096x1024 bf16 =  8 MiB
    bf16* Vt   = xb;                           //  reuse xb: 2x16x64x2048 bf16 = 8 MiB

    cast_f32_bf16_kernel<<<4096, 256, 0, stream>>>(x, xb, 1048576);
    transpose_cast_kernel<<<dim3(48, 16), 256, 0, stream>>>(W_attn, WaT, 1024, 3072);
    transpose_cast_kernel<<<dim3(16, 16), 256, 0, stream>>>(W_proj, WpT, 1024, 1024);

    gemm256_kernel<<<192, 512, 0, stream>>>(xb, WaT, qkv, 4096, 3072, 1024);
    transpose_v_kernel<<<1024, 256, 0, stream>>>(qkv, Vt);
    attn_kernel<<<512, 512, 0, stream>>>(qkv, Vt, yatt);
    gemm_bt_kernel<false><<<dim3(8, 32), 256, 0, stream>>>(yatt, WpT, nullptr, out, 4096, 1024, 1024);
}

// Round 8
// 105.185 us; speedup vs baseline: 1.3073x; 1.0379x over previous
//
#include <hip/hip_runtime.h>

typedef __bf16 bf16;
typedef __bf16 bf16x4 __attribute__((ext_vector_type(4)));
typedef __bf16 bf16x8 __attribute__((ext_vector_type(8)));
typedef float f32x4 __attribute__((ext_vector_type(4)));

#define T_SEQ 2048
#define CDIM  1024
#define QKV_LD 3072
#define MEM   256

// global -> LDS direct DMA, 16B per lane. LDS dest is wave-uniform base + lane*16B.
#define GLOAD_LDS16(gp, lp) __builtin_amdgcn_global_load_lds( \
    (const __attribute__((address_space(1))) unsigned int*)(gp), \
    (__attribute__((address_space(3))) unsigned int*)(lp), 16, 0, 0)

#define BAR() do { __builtin_amdgcn_s_barrier(); asm volatile("" ::: "memory"); } while (0)

// ---------------- cast f32 -> bf16 (vectorized x4) ----------------
__global__ __launch_bounds__(256) void cast_f32_bf16_kernel(const float* __restrict__ in,
                                                            bf16* __restrict__ out, int n4) {
    int i = blockIdx.x * 256 + threadIdx.x;
    if (i < n4) {
        float4 v = reinterpret_cast<const float4*>(in)[i];
        bf16x4 o = { (bf16)v.x, (bf16)v.y, (bf16)v.z, (bf16)v.w };
        reinterpret_cast<bf16x4*>(out)[i] = o;
    }
}

// ------------- transpose+cast: W[K][N] f32 -> Wt[N][K] bf16 -------------
__global__ __launch_bounds__(256) void transpose_cast_kernel(const float* __restrict__ W,
                                                             bf16* __restrict__ Wt,
                                                             int K, int N) {
    __shared__ float tile[64][65];
    const int n0 = blockIdx.x * 64;
    const int k0 = blockIdx.y * 64;
    const int t  = threadIdx.x;
    const int tr = t >> 4;
    const int tc = (t & 15) * 4;
#pragma unroll
    for (int it = 0; it < 4; ++it) {
        int r = it * 16 + tr;
        float4 v = *reinterpret_cast<const float4*>(&W[(size_t)(k0 + r) * N + n0 + tc]);
        tile[r][tc + 0] = v.x; tile[r][tc + 1] = v.y;
        tile[r][tc + 2] = v.z; tile[r][tc + 3] = v.w;
    }
    __syncthreads();
#pragma unroll
    for (int it = 0; it < 4; ++it) {
        int n = it * 16 + tr;
        bf16x4 o;
#pragma unroll
        for (int j = 0; j < 4; ++j) o[j] = (bf16)tile[tc + j][n];
        *reinterpret_cast<bf16x4*>(&Wt[(size_t)(n0 + n) * K + k0 + tc]) = o;
    }
}

// ------------- transpose V third of qkv: [T][64] per (b,h) -> Vt[b][h][64][T] -------------
__global__ __launch_bounds__(256) void transpose_v_kernel(const bf16* __restrict__ qkv,
                                                          bf16* __restrict__ Vt) {
    const int bid = blockIdx.x;
    const int tt = bid & 31, h = (bid >> 5) & 15, b = bid >> 9;
    __shared__ bf16 tile[64][72];
    const int i = threadIdx.x;
    {
        const int tr = i >> 2, dc = (i & 3) * 16;
        const bf16* src = qkv + (size_t)(b * T_SEQ + tt * 64 + tr) * QKV_LD + 2 * CDIM + h * 64 + dc;
        *reinterpret_cast<bf16x8*>(&tile[tr][dc])     = *reinterpret_cast<const bf16x8*>(src);
        *reinterpret_cast<bf16x8*>(&tile[tr][dc + 8]) = *reinterpret_cast<const bf16x8*>(src + 8);
    }
    __syncthreads();
    {
        const int dr = i >> 2, tc = (i & 3) * 16;
        bf16x8 o0, o1;
#pragma unroll
        for (int j = 0; j < 8; ++j) { o0[j] = tile[tc + j][dr]; o1[j] = tile[tc + 8 + j][dr]; }
        bf16* dst = Vt + ((size_t)((b * 16 + h) * 64 + dr)) * T_SEQ + tt * 64 + tc;
        *reinterpret_cast<bf16x8*>(dst)     = o0;
        *reinterpret_cast<bf16x8*>(dst + 8) = o1;
    }
}

// ------------- 256x192 GEMM, fine-interleaved pipeline: C = A[M][K] * Bt[N][K]^T -------------
// Retile of R5's 256x256: grid = (M/256)*(N/192) = 256 blocks = 1/CU (was 192 -> 64 CUs idle).
// 8 waves (2M x 4N); per-wave C = 128x48 (8 m-frags x 3 n-frags). BK=64, dbuf LDS 112KiB.
// Staging in 64-row units: A=4, B=3 per K-tile; counted vmcnt(4) (= A-units of tile t+2).
__global__ __launch_bounds__(512, 1) void gemm256_kernel(const bf16* __restrict__ A,
                                                         const bf16* __restrict__ Bt,
                                                         bf16* __restrict__ Cb,
                                                         int M, int N, int K) {
    __shared__ bf16 smA[2][256][64];
    __shared__ bf16 smB[2][192][64];
    const int t    = threadIdx.x;
    const int lane = t & 63;
    const int w    = t >> 6;
    const int wm   = (w >> 2) * 128;     // wave row-half
    const int wn   = (w & 3) * 48;       // wave col-quarter (3 frags of 16)
    const int g    = lane >> 4;
    const int r    = lane & 15;

    const int nwg = gridDim.x, cpx = nwg >> 3;           // 256 % 8 == 0 -> bijective
    const int swz = (blockIdx.x & 7) * cpx + (blockIdx.x >> 3);
    const int ntn = N / 192;
    const int m0 = (swz / ntn) * 256;
    const int n0 = (swz % ntn) * 192;

    const bf16* Ab = A  + (size_t)m0 * K;
    const bf16* Bb = Bt + (size_t)n0 * K;
    const int NT = K >> 6;               // K-tiles of 64

    // stage one 64-row unit (u): rows u*64 + w*8 + (lane>>3); source chunk pre-swizzled
#define STAGE_A(bi, u, kt) do { \
        const bf16* _s = Ab + (size_t)((u) * 64 + w * 8 + (lane >> 3)) * K \
                         + (kt) * 64 + ((lane & 7) ^ (lane >> 3)) * 8; \
        GLOAD_LDS16(_s, &smA[bi][(u) * 64 + w * 8][0]); \
    } while (0)
#define STAGE_B(bi, u, kt) do { \
        const bf16* _s = Bb + (size_t)((u) * 64 + w * 8 + (lane >> 3)) * K \
                         + (kt) * 64 + ((lane & 7) ^ (lane >> 3)) * 8; \
        GLOAD_LDS16(_s, &smB[bi][(u) * 64 + w * 8][0]); \
    } while (0)

    const int ch0 = ((g     ) ^ (r & 7)) * 8;   // read-side swizzle (row&7 == r&7)
    const int ch1 = ((g ^ 4) ^ (r & 7)) * 8;

    const f32x4 zero4 = {0.f, 0.f, 0.f, 0.f};
    f32x4 acc[8][3];
#pragma unroll
    for (int i = 0; i < 8; ++i)
#pragma unroll
        for (int j = 0; j < 3; ++j) acc[i][j] = zero4;

    bf16x8 afr0[4][2], afr1[4][2], bfrA[2][2], bfrB[1][2];

    // MFMA group: 4 m-frags x NF n-frags x 2 kh
#define MGRP(AF, FMB, BF, FNB, NF) do { \
    __builtin_amdgcn_s_setprio(1); \
    _Pragma("unroll") \
    for (int fm2 = 0; fm2 < 4; ++fm2) \
    _Pragma("unroll") \
    for (int fn2 = 0; fn2 < (NF); ++fn2) \
    _Pragma("unroll") \
    for (int kh = 0; kh < 2; ++kh) \
        acc[(FMB)+fm2][(FNB)+fn2] = __builtin_amdgcn_mfma_f32_16x16x32_bf16( \
            AF[fm2][kh], BF[fn2][kh], acc[(FMB)+fm2][(FNB)+fn2], 0, 0, 0); \
    __builtin_amdgcn_s_setprio(0); } while (0)

    // ---- prologue: T0 all 7 units + T1 A-units; wait T0 landed (4 = T1's A in flight) ----
    STAGE_A(0, 0, 0); STAGE_A(0, 1, 0); STAGE_A(0, 2, 0); STAGE_A(0, 3, 0);
    STAGE_B(0, 0, 0); STAGE_B(0, 1, 0); STAGE_B(0, 2, 0);
    STAGE_A(1, 0, 1); STAGE_A(1, 1, 1); STAGE_A(1, 2, 1); STAGE_A(1, 3, 1);
    asm volatile("s_waitcnt vmcnt(4)" ::: "memory");
    __builtin_amdgcn_sched_barrier(0);
    BAR();

    for (int kt = 0; kt < NT; ++kt) {
        const int cur = kt & 1, nxt = cur ^ 1;
        // ---- R0 (12 reads): afr0 + bfrA — feeds M0 ----
#pragma unroll
        for (int i = 0; i < 4; ++i) {
            afr0[i][0] = *reinterpret_cast<const bf16x8*>(&smA[cur][wm + i * 16 + r][ch0]);
            afr0[i][1] = *reinterpret_cast<const bf16x8*>(&smA[cur][wm + i * 16 + r][ch1]);
        }
#pragma unroll
        for (int fn = 0; fn < 2; ++fn) {
            bfrA[fn][0] = *reinterpret_cast<const bf16x8*>(&smB[cur][wn + fn * 16 + r][ch0]);
            bfrA[fn][1] = *reinterpret_cast<const bf16x8*>(&smB[cur][wn + fn * 16 + r][ch1]);
        }
        // ---- R1 (8 reads): afr1 — feeds M1 ----
#pragma unroll
        for (int i = 0; i < 4; ++i) {
            afr1[i][0] = *reinterpret_cast<const bf16x8*>(&smA[cur][wm + 64 + i * 16 + r][ch0]);
            afr1[i][1] = *reinterpret_cast<const bf16x8*>(&smA[cur][wm + 64 + i * 16 + r][ch1]);
        }
        // ---- R2 (2 reads): bfrB — feeds M2/M3 ----
        bfrB[0][0] = *reinterpret_cast<const bf16x8*>(&smB[cur][wn + 32 + r][ch0]);
        bfrB[0][1] = *reinterpret_cast<const bf16x8*>(&smB[cur][wn + 32 + r][ch1]);
        // stage next tile's B units (buffer nxt; its B region was consumed last iter)
        if (kt + 1 < NT) { STAGE_B(nxt, 0, kt + 1); STAGE_B(nxt, 1, kt + 1); STAGE_B(nxt, 2, kt + 1); }
        __builtin_amdgcn_sched_barrier(0);
        BAR();                                // all waves' reads of buf[cur] issued

        // ---- 4 MFMA groups; A-units of tile kt+2 interleaved (cur buf, A reads done) ----
        MGRP(afr0, 0, bfrA, 0, 2);            // 16 MFMA, waits R0
        if (kt + 2 < NT) STAGE_A(cur, 0, kt + 2);
        MGRP(afr1, 4, bfrA, 0, 2);            // 16 MFMA, waits R1
        if (kt + 2 < NT) { STAGE_A(cur, 1, kt + 2); STAGE_A(cur, 2, kt + 2); }
        MGRP(afr1, 4, bfrB, 2, 1);            // 8 MFMA, waits R2
        if (kt + 2 < NT) STAGE_A(cur, 3, kt + 2);
        MGRP(afr0, 0, bfrB, 2, 1);            // 8 MFMA, no wait

        if (kt >= NT - 2)      { asm volatile("s_waitcnt vmcnt(0)" ::: "memory"); }
        else                   { asm volatile("s_waitcnt vmcnt(4)" ::: "memory"); }
        __builtin_amdgcn_sched_barrier(0);
        BAR();                                // next tile landed; safe to read
    }

    // ---- epilogue: C/D layout col = lane&15, row = 4*(lane>>4)+e ----
#pragma unroll
    for (int fm = 0; fm < 8; ++fm)
#pragma unroll
        for (int fn = 0; fn < 3; ++fn)
#pragma unroll
            for (int e = 0; e < 4; ++e) {
                int row = m0 + wm + fm * 16 + g * 4 + e;
                int col = n0 + wn + fn * 16 + r;
                Cb[(size_t)row * N + col] = (bf16)acc[fm][fn][e];
            }
#undef STAGE_A
#undef STAGE_B
#undef MGRP
}

// ------------- GEMM: C[M][N] = A[M][K] * Bt[N][K]^T  (m97 structure, proj; frozen) -------------
template<bool OUT_BF16>
__global__ __launch_bounds__(256) void gemm_bt_kernel(const bf16* __restrict__ A,
                                                      const bf16* __restrict__ Bt,
                                                      bf16* __restrict__ Cb,
                                                      float* __restrict__ Cf,
                                                      int M, int N, int K) {
    __shared__ bf16 As[128 * 32];
    __shared__ bf16 Bs[128 * 32];
    const int t    = threadIdx.x;
    const int lane = t & 63;
    const int w    = t >> 6;
    const int wm   = (w >> 1) * 64;
    const int wn   = (w & 1) * 64;
    const int g    = lane >> 4;
    const int r    = lane & 15;
    const int m0   = blockIdx.y * 128;
    const int n0   = blockIdx.x * 128;

    const bf16* Ab = A  + (size_t)m0 * K;
    const bf16* Bb = Bt + (size_t)n0 * K;
    const bf16* Ag0 = Ab + (size_t)(w * 32 + (lane >> 2)) * K + (lane & 3) * 8;
    const bf16* Ag1 = Ab + (size_t)(w * 32 + 16 + (lane >> 2)) * K + (lane & 3) * 8;
    const bf16* Bg0 = Bb + (size_t)(w * 32 + (lane >> 2)) * K + (lane & 3) * 8;
    const bf16* Bg1 = Bb + (size_t)(w * 32 + 16 + (lane >> 2)) * K + (lane & 3) * 8;

    bf16* ldsA0 = As + (w * 32) * 32;
    bf16* ldsA1 = As + (w * 32 + 16) * 32;
    bf16* ldsB0 = Bs + (w * 32) * 32;
    bf16* ldsB1 = Bs + (w * 32 + 16) * 32;

    const f32x4 zero4 = {0.f, 0.f, 0.f, 0.f};
    f32x4 acc[4][4];
#pragma unroll
    for (int i = 0; i < 4; ++i)
#pragma unroll
        for (int j = 0; j < 4; ++j) acc[i][j] = zero4;

    for (int k0 = 0; k0 < K; k0 += 32) {
        __syncthreads();
        GLOAD_LDS16(Ag0 + k0, ldsA0);
        GLOAD_LDS16(Ag1 + k0, ldsA1);
        GLOAD_LDS16(Bg0 + k0, ldsB0);
        GLOAD_LDS16(Bg1 + k0, ldsB1);
        __syncthreads();

        bf16x8 af[4], bfr[4];
#pragma unroll
        for (int i = 0; i < 4; ++i) {
            af[i]  = *reinterpret_cast<const bf16x8*>(&As[(wm + i * 16 + r) * 32 + g * 8]);
            bfr[i] = *reinterpret_cast<const bf16x8*>(&Bs[(wn + i * 16 + r) * 32 + g * 8]);
        }
#pragma unroll
        for (int i = 0; i < 4; ++i)
#pragma unroll
            for (int j = 0; j < 4; ++j)
                acc[i][j] = __builtin_amdgcn_mfma_f32_16x16x32_bf16(af[i], bfr[j], acc[i][j], 0, 0, 0);
    }

#pragma unroll
    for (int i = 0; i < 4; ++i)
#pragma unroll
        for (int j = 0; j < 4; ++j)
#pragma unroll
            for (int e = 0; e < 4; ++e) {
                int row = m0 + wm + i * 16 + g * 4 + e;
                int col = n0 + wn + j * 16 + r;
                if constexpr (OUT_BF16) Cb[(size_t)row * N + col] = (bf16)acc[i][j][e];
                else                    Cf[(size_t)row * N + col] = acc[i][j][e];
            }
}

// ------------- banded flash attention v4.1 (frozen from R7) -------------
__global__ __launch_bounds__(512) void attn_kernel(const bf16* __restrict__ qkv,
                                                   const bf16* __restrict__ Vt,
                                                   bf16* __restrict__ y) {
    __shared__ bf16 vtl[64 * 384];       // linear, no pad; swizzle via source/read XOR
    const int bid  = blockIdx.x;
    const int bh   = bid >> 4;
    const int qblk = bid & 15;
    const int b = bh >> 4, h = bh & 15;
    const int qb0 = qblk * 128;
    const int wlo = qb0 - 256;           // window start (may be negative)
    const int wv   = threadIdx.x >> 6;   // wave 0..7
    const int lane = threadIdx.x & 63;
    const int g = lane >> 4, c = lane & 15;
    const int q0 = qb0 + wv * 16;
    const int q = q0 + c;
    const float NEG_INF = -__builtin_inff();

    const bf16* base = qkv + (size_t)b * T_SEQ * QKV_LD;
    const bf16* Qb = base + h * 64;
    const bf16* Kb = base + CDIM + h * 64;
    const bf16* Vtb = Vt + (size_t)(b * 16 + h) * 64 * T_SEQ;

    // ---- stage V^T window: 48KB linear, 6 gload issues/wave; source pre-swizzled (x = d&14)
#pragma unroll
    for (int i = 0; i < 6; ++i) {
        const int Lb = (wv * 6 + i) * 1024 + lane * 16;  // linear LDS byte this lane covers
        const int d   = Lb / 768;
        const int c16 = (Lb % 768) >> 4;                 // 16B-pair index within row
        int koff = ((2 * c16) ^ (d & 14)) << 2;          // logical elem offset of this 16B
        int gk = wlo + koff;
        gk = gk < 0 ? 0 : gk;                            // clamp (region masked in compute)
        GLOAD_LDS16(Vtb + (size_t)d * T_SEQ + gk, vtl + (wv * 6 + i) * 512);
    }

    const bf16x8 qf0 = *reinterpret_cast<const bf16x8*>(Qb + (size_t)q * QKV_LD + g * 8);
    const bf16x8 qf1 = *reinterpret_cast<const bf16x8*>(Qb + (size_t)q * QKV_LD + 32 + g * 8);

    __syncthreads();

    const f32x4 zero4 = {0.f, 0.f, 0.f, 0.f};
    f32x4 o[4];
#pragma unroll
    for (int cb = 0; cb < 4; ++cb) o[cb] = zero4;
    float m_run = NEG_INF, l_run = 0.f;

    const int jstart = (q0 - MEM > 0) ? (q0 - MEM) : 0;
    for (int j0 = jstart; j0 < q0 + 16; j0 += 32) {
        // --- S^T = mfma(K, Q) for 32 keys ---
        const int kr0 = j0 + c;
        int kr1 = j0 + 16 + c; kr1 = kr1 < T_SEQ ? kr1 : T_SEQ - 1;
        bf16x8 kf00 = *reinterpret_cast<const bf16x8*>(Kb + (size_t)kr0 * QKV_LD + g * 8);
        bf16x8 kf01 = *reinterpret_cast<const bf16x8*>(Kb + (size_t)kr0 * QKV_LD + 32 + g * 8);
        bf16x8 kf10 = *reinterpret_cast<const bf16x8*>(Kb + (size_t)kr1 * QKV_LD + g * 8);
        bf16x8 kf11 = *reinterpret_cast<const bf16x8*>(Kb + (size_t)kr1 * QKV_LD + 32 + g * 8);
        f32x4 s0 = __builtin_amdgcn_mfma_f32_16x16x32_bf16(kf00, qf0, zero4, 0, 0, 0);
        s0 = __builtin_amdgcn_mfma_f32_16x16x32_bf16(kf01, qf1, s0, 0, 0, 0);
        f32x4 s1 = __builtin_amdgcn_mfma_f32_16x16x32_bf16(kf10, qf0, zero4, 0, 0, 0);
        s1 = __builtin_amdgcn_mfma_f32_16x16x32_bf16(kf11, qf1, s1, 0, 0, 0);

        // --- scale + band mask; S^T value (lane,e) = S[key=j0+4g+e(+16)][q=c] ---
        float mt = NEG_INF;
#pragma unroll
        for (int e = 0; e < 4; ++e) {
            int k0i = j0 + 4 * g + e;
            int k1i = k0i + 16;
            float v0 = (k0i <= q && k0i >= q - MEM) ? s0[e] * 0.125f : NEG_INF;
            float v1 = (k1i <= q && k1i >= q - MEM) ? s1[e] * 0.125f : NEG_INF;
            s0[e] = v0; s1[e] = v1;
            mt = fmaxf(mt, fmaxf(v0, v1));
        }
        mt = fmaxf(mt, __shfl_xor(mt, 16, 64));
        mt = fmaxf(mt, __shfl_xor(mt, 32, 64));
        const float mnew = fmaxf(m_run, mt);
        const float corr = __expf(m_run - mnew);

        float ps = 0.f;
        bf16x8 pav;
#pragma unroll
        for (int e = 0; e < 4; ++e) {
            float e0 = __expf(s0[e] - mnew);
            float e1 = __expf(s1[e] - mnew);
            ps += e0 + e1;
            pav[e]     = (bf16)e0;
            pav[4 + e] = (bf16)e1;
        }
        ps += __shfl_xor(ps, 16, 64);
        ps += __shfl_xor(ps, 32, 64);
        l_run = l_run * corr + ps;
        m_run = mnew;

        // --- O^T rescale: lane-local (q = c for all regs) ---
#pragma unroll
        for (int cb = 0; cb < 4; ++cb) {
            o[cb][0] *= corr; o[cb][1] *= corr; o[cb][2] *= corr; o[cb][3] *= corr;
        }

        // --- PV as O^T = mfma(V-frag, pav); V-frag via swizzled ds_read_b64 x2 ---
        const int jrel = j0 - wlo;
        const int c8a = (jrel + 4 * g) >> 2;       // 8B-chunk index (always 4-elem aligned)
        const int c8b = (c8a + 4 > 95) ? 95 : (c8a + 4);  // overrun => keys fully masked (P=0)
#pragma unroll
        for (int cb = 0; cb < 4; ++cb) {
            const int d = cb * 16 + c;
            const int xx = d & 14;
            const bf16* vrow = vtl + d * 384;
            bf16x4 va  = *reinterpret_cast<const bf16x4*>(vrow + ((c8a ^ xx) << 2));
            bf16x4 vb2 = *reinterpret_cast<const bf16x4*>(vrow + ((c8b ^ xx) << 2));
            bf16x8 vf = { va[0], va[1], va[2], va[3], vb2[0], vb2[1], vb2[2], vb2[3] };
            o[cb] = __builtin_amdgcn_mfma_f32_16x16x32_bf16(vf, pav, o[cb], 0, 0, 0);
        }
    }

    // --- epilogue: o[cb][e] = O[q=q0+c][d = cb*16+4g+e]; lane-local divide; bf16x4 stores ---
    const float linv = 1.0f / l_run;
    bf16* yr = y + (size_t)(b * T_SEQ + q) * CDIM + h * 64 + 4 * g;
#pragma unroll
    for (int cb = 0; cb < 4; ++cb) {
        bf16x4 ov = { (bf16)(o[cb][0] * linv), (bf16)(o[cb][1] * linv),
                      (bf16)(o[cb][2] * linv), (bf16)(o[cb][3] * linv) };
        *reinterpret_cast<bf16x4*>(yr + cb * 16) = ov;
    }
}

// ---------------- launch ----------------
extern "C" void kernel_launch(void* const* d_in, const int* in_sizes, int n_in,
                              void* d_out, int out_size, void* d_ws, size_t ws_size,
                              hipStream_t stream) {
    const float* x      = (const float*)d_in[0];
    const float* W_attn = (const float*)d_in[1];
    const float* W_proj = (const float*)d_in[2];
    float* out = (float*)d_out;

    char* ws = (char*)d_ws;
    bf16* xb   = (bf16*)(ws);                  //  4096x1024 bf16 =  8 MiB (dead after gemm256)
    bf16* WaT  = (bf16*)(ws + 8388608);        //  3072x1024 bf16 =  6 MiB
    bf16* WpT  = (bf16*)(ws + 14680064);       //  1024x1024 bf16 =  2 MiB
    bf16* qkv  = (bf16*)(ws + 16777216);       //  4096x3072 bf16 = 24 MiB
    bf16* yatt = (bf16*)(ws + 41943040);       //  4096x1024 bf16 =  8 MiB
    bf16* Vt   = xb;                           //  reuse xb: 2x16x64x2048 bf16 = 8 MiB

    cast_f32_bf16_kernel<<<4096, 256, 0, stream>>>(x, xb, 1048576);
    transpose_cast_kernel<<<dim3(48, 16), 256, 0, stream>>>(W_attn, WaT, 1024, 3072);
    transpose_cast_kernel<<<dim3(16, 16), 256, 0, stream>>>(W_proj, WpT, 1024, 1024);

    gemm256_kernel<<<256, 512, 0, stream>>>(xb, WaT, qkv, 4096, 3072, 1024);
    transpose_v_kernel<<<1024, 256, 0, stream>>>(qkv, Vt);
    attn_kernel<<<512, 512, 0, stream>>>(qkv, Vt, yatt);
    gemm_bt_kernel<false><<<dim3(8, 32), 256, 0, stream>>>(yatt, WpT, nullptr, out, 4096, 1024, 1024);
}

// Round 9
// 102.136 us; speedup vs baseline: 1.3463x; 1.0299x over previous
//
#include <hip/hip_runtime.h>

typedef __bf16 bf16;
typedef __bf16 bf16x4 __attribute__((ext_vector_type(4)));
typedef __bf16 bf16x8 __attribute__((ext_vector_type(8)));
typedef float f32x4 __attribute__((ext_vector_type(4)));

#define T_SEQ 2048
#define CDIM  1024
#define QKV_LD 3072
#define MEM   256

// global -> LDS direct DMA, 16B per lane. LDS dest is wave-uniform base + lane*16B.
#define GLOAD_LDS16(gp, lp) __builtin_amdgcn_global_load_lds( \
    (const __attribute__((address_space(1))) unsigned int*)(gp), \
    (__attribute__((address_space(3))) unsigned int*)(lp), 16, 0, 0)

#define BAR() do { __builtin_amdgcn_s_barrier(); asm volatile("" ::: "memory"); } while (0)

// ---------------- cast f32 -> bf16 (vectorized x4) ----------------
__global__ __launch_bounds__(256) void cast_f32_bf16_kernel(const float* __restrict__ in,
                                                            bf16* __restrict__ out, int n4) {
    int i = blockIdx.x * 256 + threadIdx.x;
    if (i < n4) {
        float4 v = reinterpret_cast<const float4*>(in)[i];
        bf16x4 o = { (bf16)v.x, (bf16)v.y, (bf16)v.z, (bf16)v.w };
        reinterpret_cast<bf16x4*>(out)[i] = o;
    }
}

// ------------- transpose+cast: W[K][N] f32 -> Wt[N][K] bf16 -------------
__global__ __launch_bounds__(256) void transpose_cast_kernel(const float* __restrict__ W,
                                                             bf16* __restrict__ Wt,
                                                             int K, int N) {
    __shared__ float tile[64][65];
    const int n0 = blockIdx.x * 64;
    const int k0 = blockIdx.y * 64;
    const int t  = threadIdx.x;
    const int tr = t >> 4;
    const int tc = (t & 15) * 4;
#pragma unroll
    for (int it = 0; it < 4; ++it) {
        int r = it * 16 + tr;
        float4 v = *reinterpret_cast<const float4*>(&W[(size_t)(k0 + r) * N + n0 + tc]);
        tile[r][tc + 0] = v.x; tile[r][tc + 1] = v.y;
        tile[r][tc + 2] = v.z; tile[r][tc + 3] = v.w;
    }
    __syncthreads();
#pragma unroll
    for (int it = 0; it < 4; ++it) {
        int n = it * 16 + tr;
        bf16x4 o;
#pragma unroll
        for (int j = 0; j < 4; ++j) o[j] = (bf16)tile[tc + j][n];
        *reinterpret_cast<bf16x4*>(&Wt[(size_t)(n0 + n) * K + k0 + tc]) = o;
    }
}

// ------------- 256x192 GEMM, fine-interleaved, V-transposing epilogue -------------
// As R8 but: output cols >= 2048 (the V third of qkv) are written DIRECTLY to
// Vt[b][h][d][t] via bf16x4 stores (acc's 4 elems = consecutive t at fixed d),
// removing the separate transpose_v kernel (16 MB round-trip + 1 launch).
__global__ __launch_bounds__(512, 1) void gemm256_kernel(const bf16* __restrict__ A,
                                                         const bf16* __restrict__ Bt,
                                                         bf16* __restrict__ Cb,
                                                         bf16* __restrict__ Vt,
                                                         int M, int N, int K) {
    __shared__ bf16 smA[2][256][64];
    __shared__ bf16 smB[2][192][64];
    const int t    = threadIdx.x;
    const int lane = t & 63;
    const int w    = t >> 6;
    const int wm   = (w >> 2) * 128;     // wave row-half
    const int wn   = (w & 3) * 48;       // wave col-quarter (3 frags of 16)
    const int g    = lane >> 4;
    const int r    = lane & 15;

    const int nwg = gridDim.x, cpx = nwg >> 3;           // 256 % 8 == 0 -> bijective
    const int swz = (blockIdx.x & 7) * cpx + (blockIdx.x >> 3);
    const int ntn = N / 192;
    const int m0 = (swz / ntn) * 256;
    const int n0 = (swz % ntn) * 192;

    const bf16* Ab = A  + (size_t)m0 * K;
    const bf16* Bb = Bt + (size_t)n0 * K;
    const int NT = K >> 6;               // K-tiles of 64

#define STAGE_A(bi, u, kt) do { \
        const bf16* _s = Ab + (size_t)((u) * 64 + w * 8 + (lane >> 3)) * K \
                         + (kt) * 64 + ((lane & 7) ^ (lane >> 3)) * 8; \
        GLOAD_LDS16(_s, &smA[bi][(u) * 64 + w * 8][0]); \
    } while (0)
#define STAGE_B(bi, u, kt) do { \
        const bf16* _s = Bb + (size_t)((u) * 64 + w * 8 + (lane >> 3)) * K \
                         + (kt) * 64 + ((lane & 7) ^ (lane >> 3)) * 8; \
        GLOAD_LDS16(_s, &smB[bi][(u) * 64 + w * 8][0]); \
    } while (0)

    const int ch0 = ((g     ) ^ (r & 7)) * 8;   // read-side swizzle (row&7 == r&7)
    const int ch1 = ((g ^ 4) ^ (r & 7)) * 8;

    const f32x4 zero4 = {0.f, 0.f, 0.f, 0.f};
    f32x4 acc[8][3];
#pragma unroll
    for (int i = 0; i < 8; ++i)
#pragma unroll
        for (int j = 0; j < 3; ++j) acc[i][j] = zero4;

    bf16x8 afr0[4][2], afr1[4][2], bfrA[2][2], bfrB[1][2];

#define MGRP(AF, FMB, BF, FNB, NF) do { \
    __builtin_amdgcn_s_setprio(1); \
    _Pragma("unroll") \
    for (int fm2 = 0; fm2 < 4; ++fm2) \
    _Pragma("unroll") \
    for (int fn2 = 0; fn2 < (NF); ++fn2) \
    _Pragma("unroll") \
    for (int kh = 0; kh < 2; ++kh) \
        acc[(FMB)+fm2][(FNB)+fn2] = __builtin_amdgcn_mfma_f32_16x16x32_bf16( \
            AF[fm2][kh], BF[fn2][kh], acc[(FMB)+fm2][(FNB)+fn2], 0, 0, 0); \
    __builtin_amdgcn_s_setprio(0); } while (0)

    // ---- prologue ----
    STAGE_A(0, 0, 0); STAGE_A(0, 1, 0); STAGE_A(0, 2, 0); STAGE_A(0, 3, 0);
    STAGE_B(0, 0, 0); STAGE_B(0, 1, 0); STAGE_B(0, 2, 0);
    STAGE_A(1, 0, 1); STAGE_A(1, 1, 1); STAGE_A(1, 2, 1); STAGE_A(1, 3, 1);
    asm volatile("s_waitcnt vmcnt(4)" ::: "memory");
    __builtin_amdgcn_sched_barrier(0);
    BAR();

    for (int kt = 0; kt < NT; ++kt) {
        const int cur = kt & 1, nxt = cur ^ 1;
#pragma unroll
        for (int i = 0; i < 4; ++i) {
            afr0[i][0] = *reinterpret_cast<const bf16x8*>(&smA[cur][wm + i * 16 + r][ch0]);
            afr0[i][1] = *reinterpret_cast<const bf16x8*>(&smA[cur][wm + i * 16 + r][ch1]);
        }
#pragma unroll
        for (int fn = 0; fn < 2; ++fn) {
            bfrA[fn][0] = *reinterpret_cast<const bf16x8*>(&smB[cur][wn + fn * 16 + r][ch0]);
            bfrA[fn][1] = *reinterpret_cast<const bf16x8*>(&smB[cur][wn + fn * 16 + r][ch1]);
        }
#pragma unroll
        for (int i = 0; i < 4; ++i) {
            afr1[i][0] = *reinterpret_cast<const bf16x8*>(&smA[cur][wm + 64 + i * 16 + r][ch0]);
            afr1[i][1] = *reinterpret_cast<const bf16x8*>(&smA[cur][wm + 64 + i * 16 + r][ch1]);
        }
        bfrB[0][0] = *reinterpret_cast<const bf16x8*>(&smB[cur][wn + 32 + r][ch0]);
        bfrB[0][1] = *reinterpret_cast<const bf16x8*>(&smB[cur][wn + 32 + r][ch1]);
        if (kt + 1 < NT) { STAGE_B(nxt, 0, kt + 1); STAGE_B(nxt, 1, kt + 1); STAGE_B(nxt, 2, kt + 1); }
        __builtin_amdgcn_sched_barrier(0);
        BAR();

        MGRP(afr0, 0, bfrA, 0, 2);
        if (kt + 2 < NT) STAGE_A(cur, 0, kt + 2);
        MGRP(afr1, 4, bfrA, 0, 2);
        if (kt + 2 < NT) { STAGE_A(cur, 1, kt + 2); STAGE_A(cur, 2, kt + 2); }
        MGRP(afr1, 4, bfrB, 2, 1);
        if (kt + 2 < NT) STAGE_A(cur, 3, kt + 2);
        MGRP(afr0, 0, bfrB, 2, 1);

        if (kt >= NT - 2)      { asm volatile("s_waitcnt vmcnt(0)" ::: "memory"); }
        else                   { asm volatile("s_waitcnt vmcnt(4)" ::: "memory"); }
        __builtin_amdgcn_sched_barrier(0);
        BAR();
    }

    // ---- epilogue: Q/K cols -> qkv rows; V cols (>=2048) -> Vt[b][h][d][t] (bf16x4) ----
#pragma unroll
    for (int fm = 0; fm < 8; ++fm)
#pragma unroll
        for (int fn = 0; fn < 3; ++fn) {
            const int col  = n0 + wn + fn * 16 + r;
            const int row0 = m0 + wm + fm * 16 + g * 4;
            if (col < 2 * CDIM) {
#pragma unroll
                for (int e = 0; e < 4; ++e)
                    Cb[(size_t)(row0 + e) * N + col] = (bf16)acc[fm][fn][e];
            } else {
                const int hd = col - 2 * CDIM;
                const int bb = row0 >> 11, tt = row0 & (T_SEQ - 1);
                bf16x4 v = { (bf16)acc[fm][fn][0], (bf16)acc[fm][fn][1],
                             (bf16)acc[fm][fn][2], (bf16)acc[fm][fn][3] };
                *reinterpret_cast<bf16x4*>(&Vt[((size_t)(bb * 16 + (hd >> 6)) * 64 + (hd & 63)) * T_SEQ + tt]) = v;
            }
        }
#undef STAGE_A
#undef STAGE_B
#undef MGRP
}

// ------------- GEMM: C[M][N] = A[M][K] * Bt[N][K]^T  (m97 structure, proj; frozen) -------------
template<bool OUT_BF16>
__global__ __launch_bounds__(256) void gemm_bt_kernel(const bf16* __restrict__ A,
                                                      const bf16* __restrict__ Bt,
                                                      bf16* __restrict__ Cb,
                                                      float* __restrict__ Cf,
                                                      int M, int N, int K) {
    __shared__ bf16 As[128 * 32];
    __shared__ bf16 Bs[128 * 32];
    const int t    = threadIdx.x;
    const int lane = t & 63;
    const int w    = t >> 6;
    const int wm   = (w >> 1) * 64;
    const int wn   = (w & 1) * 64;
    const int g    = lane >> 4;
    const int r    = lane & 15;
    const int m0   = blockIdx.y * 128;
    const int n0   = blockIdx.x * 128;

    const bf16* Ab = A  + (size_t)m0 * K;
    const bf16* Bb = Bt + (size_t)n0 * K;
    const bf16* Ag0 = Ab + (size_t)(w * 32 + (lane >> 2)) * K + (lane & 3) * 8;
    const bf16* Ag1 = Ab + (size_t)(w * 32 + 16 + (lane >> 2)) * K + (lane & 3) * 8;
    const bf16* Bg0 = Bb + (size_t)(w * 32 + (lane >> 2)) * K + (lane & 3) * 8;
    const bf16* Bg1 = Bb + (size_t)(w * 32 + 16 + (lane >> 2)) * K + (lane & 3) * 8;

    bf16* ldsA0 = As + (w * 32) * 32;
    bf16* ldsA1 = As + (w * 32 + 16) * 32;
    bf16* ldsB0 = Bs + (w * 32) * 32;
    bf16* ldsB1 = Bs + (w * 32 + 16) * 32;

    const f32x4 zero4 = {0.f, 0.f, 0.f, 0.f};
    f32x4 acc[4][4];
#pragma unroll
    for (int i = 0; i < 4; ++i)
#pragma unroll
        for (int j = 0; j < 4; ++j) acc[i][j] = zero4;

    for (int k0 = 0; k0 < K; k0 += 32) {
        __syncthreads();
        GLOAD_LDS16(Ag0 + k0, ldsA0);
        GLOAD_LDS16(Ag1 + k0, ldsA1);
        GLOAD_LDS16(Bg0 + k0, ldsB0);
        GLOAD_LDS16(Bg1 + k0, ldsB1);
        __syncthreads();

        bf16x8 af[4], bfr[4];
#pragma unroll
        for (int i = 0; i < 4; ++i) {
            af[i]  = *reinterpret_cast<const bf16x8*>(&As[(wm + i * 16 + r) * 32 + g * 8]);
            bfr[i] = *reinterpret_cast<const bf16x8*>(&Bs[(wn + i * 16 + r) * 32 + g * 8]);
        }
#pragma unroll
        for (int i = 0; i < 4; ++i)
#pragma unroll
            for (int j = 0; j < 4; ++j)
                acc[i][j] = __builtin_amdgcn_mfma_f32_16x16x32_bf16(af[i], bfr[j], acc[i][j], 0, 0, 0);
    }

#pragma unroll
    for (int i = 0; i < 4; ++i)
#pragma unroll
        for (int j = 0; j < 4; ++j)
#pragma unroll
            for (int e = 0; e < 4; ++e) {
                int row = m0 + wm + i * 16 + g * 4 + e;
                int col = n0 + wn + j * 16 + r;
                if constexpr (OUT_BF16) Cb[(size_t)row * N + col] = (bf16)acc[i][j][e];
                else                    Cf[(size_t)row * N + col] = acc[i][j][e];
            }
}

// ------------- banded flash attention v5: v4.1 + K-prefetch software pipeline -------------
// Next j0-tile's 4 global K-loads are issued BEFORE the current tile's MFMA/softmax/PV,
// hiding K-load latency under ~600cy of compute (T14 issue-early). Prefetch only when
// j0+32 is a real iteration, so all addresses stay in the proven clamp envelope.
__global__ __launch_bounds__(512) void attn_kernel(const bf16* __restrict__ qkv,
                                                   const bf16* __restrict__ Vt,
                                                   bf16* __restrict__ y) {
    __shared__ bf16 vtl[64 * 384];       // linear, no pad; swizzle via source/read XOR
    const int bid  = blockIdx.x;
    const int bh   = bid >> 4;
    const int qblk = bid & 15;
    const int b = bh >> 4, h = bh & 15;
    const int qb0 = qblk * 128;
    const int wlo = qb0 - 256;           // window start (may be negative)
    const int wv   = threadIdx.x >> 6;   // wave 0..7
    const int lane = threadIdx.x & 63;
    const int g = lane >> 4, c = lane & 15;
    const int q0 = qb0 + wv * 16;
    const int q = q0 + c;
    const float NEG_INF = -__builtin_inff();

    const bf16* base = qkv + (size_t)b * T_SEQ * QKV_LD;
    const bf16* Qb = base + h * 64;
    const bf16* Kb = base + CDIM + h * 64;
    const bf16* Vtb = Vt + (size_t)(b * 16 + h) * 64 * T_SEQ;

    // ---- stage V^T window: 48KB linear, 6 gload issues/wave; source pre-swizzled (x = d&14)
#pragma unroll
    for (int i = 0; i < 6; ++i) {
        const int Lb = (wv * 6 + i) * 1024 + lane * 16;  // linear LDS byte this lane covers
        const int d   = Lb / 768;
        const int c16 = (Lb % 768) >> 4;                 // 16B-pair index within row
        int koff = ((2 * c16) ^ (d & 14)) << 2;          // logical elem offset of this 16B
        int gk = wlo + koff;
        gk = gk < 0 ? 0 : gk;                            // clamp (region masked in compute)
        GLOAD_LDS16(Vtb + (size_t)d * T_SEQ + gk, vtl + (wv * 6 + i) * 512);
    }

    const bf16x8 qf0 = *reinterpret_cast<const bf16x8*>(Qb + (size_t)q * QKV_LD + g * 8);
    const bf16x8 qf1 = *reinterpret_cast<const bf16x8*>(Qb + (size_t)q * QKV_LD + 32 + g * 8);

    __syncthreads();

    const f32x4 zero4 = {0.f, 0.f, 0.f, 0.f};
    f32x4 o[4];
#pragma unroll
    for (int cb = 0; cb < 4; ++cb) o[cb] = zero4;
    float m_run = NEG_INF, l_run = 0.f;

#define LOAD_K(J0, K00, K01, K10, K11) do { \
        const int _kr0 = (J0) + c; \
        int _kr1 = (J0) + 16 + c; _kr1 = _kr1 < T_SEQ ? _kr1 : T_SEQ - 1; \
        K00 = *reinterpret_cast<const bf16x8*>(Kb + (size_t)_kr0 * QKV_LD + g * 8); \
        K01 = *reinterpret_cast<const bf16x8*>(Kb + (size_t)_kr0 * QKV_LD + 32 + g * 8); \
        K10 = *reinterpret_cast<const bf16x8*>(Kb + (size_t)_kr1 * QKV_LD + g * 8); \
        K11 = *reinterpret_cast<const bf16x8*>(Kb + (size_t)_kr1 * QKV_LD + 32 + g * 8); \
    } while (0)

    const int jstart = (q0 - MEM > 0) ? (q0 - MEM) : 0;
    bf16x8 kc00, kc01, kc10, kc11;
    LOAD_K(jstart, kc00, kc01, kc10, kc11);

    for (int j0 = jstart; j0 < q0 + 16; j0 += 32) {
        // --- prefetch next tile's K (overlaps with this tile's compute) ---
        bf16x8 kn00, kn01, kn10, kn11;
        const bool more = (j0 + 32 < q0 + 16);
        if (more) LOAD_K(j0 + 32, kn00, kn01, kn10, kn11);

        // --- S^T = mfma(K, Q) for 32 keys ---
        f32x4 s0 = __builtin_amdgcn_mfma_f32_16x16x32_bf16(kc00, qf0, zero4, 0, 0, 0);
        s0 = __builtin_amdgcn_mfma_f32_16x16x32_bf16(kc01, qf1, s0, 0, 0, 0);
        f32x4 s1 = __builtin_amdgcn_mfma_f32_16x16x32_bf16(kc10, qf0, zero4, 0, 0, 0);
        s1 = __builtin_amdgcn_mfma_f32_16x16x32_bf16(kc11, qf1, s1, 0, 0, 0);

        // --- scale + band mask; S^T value (lane,e) = S[key=j0+4g+e(+16)][q=c] ---
        float mt = NEG_INF;
#pragma unroll
        for (int e = 0; e < 4; ++e) {
            int k0i = j0 + 4 * g + e;
            int k1i = k0i + 16;
            float v0 = (k0i <= q && k0i >= q - MEM) ? s0[e] * 0.125f : NEG_INF;
            float v1 = (k1i <= q && k1i >= q - MEM) ? s1[e] * 0.125f : NEG_INF;
            s0[e] = v0; s1[e] = v1;
            mt = fmaxf(mt, fmaxf(v0, v1));
        }
        mt = fmaxf(mt, __shfl_xor(mt, 16, 64));
        mt = fmaxf(mt, __shfl_xor(mt, 32, 64));
        const float mnew = fmaxf(m_run, mt);
        const float corr = __expf(m_run - mnew);

        float ps = 0.f;
        bf16x8 pav;
#pragma unroll
        for (int e = 0; e < 4; ++e) {
            float e0 = __expf(s0[e] - mnew);
            float e1 = __expf(s1[e] - mnew);
            ps += e0 + e1;
            pav[e]     = (bf16)e0;
            pav[4 + e] = (bf16)e1;
        }
        ps += __shfl_xor(ps, 16, 64);
        ps += __shfl_xor(ps, 32, 64);
        l_run = l_run * corr + ps;
        m_run = mnew;

        // --- O^T rescale: lane-local (q = c for all regs) ---
#pragma unroll
        for (int cb = 0; cb < 4; ++cb) {
            o[cb][0] *= corr; o[cb][1] *= corr; o[cb][2] *= corr; o[cb][3] *= corr;
        }

        // --- PV as O^T = mfma(V-frag, pav); V-frag via swizzled ds_read_b64 x2 ---
        const int jrel = j0 - wlo;
        const int c8a = (jrel + 4 * g) >> 2;       // 8B-chunk index (always 4-elem aligned)
        const int c8b = (c8a + 4 > 95) ? 95 : (c8a + 4);  // overrun => keys fully masked (P=0)
#pragma unroll
        for (int cb = 0; cb < 4; ++cb) {
            const int d = cb * 16 + c;
            const int xx = d & 14;
            const bf16* vrow = vtl + d * 384;
            bf16x4 va  = *reinterpret_cast<const bf16x4*>(vrow + ((c8a ^ xx) << 2));
            bf16x4 vb2 = *reinterpret_cast<const bf16x4*>(vrow + ((c8b ^ xx) << 2));
            bf16x8 vf = { va[0], va[1], va[2], va[3], vb2[0], vb2[1], vb2[2], vb2[3] };
            o[cb] = __builtin_amdgcn_mfma_f32_16x16x32_bf16(vf, pav, o[cb], 0, 0, 0);
        }

        // --- rotate prefetched K into current ---
        if (more) { kc00 = kn00; kc01 = kn01; kc10 = kn10; kc11 = kn11; }
    }
#undef LOAD_K

    // --- epilogue: o[cb][e] = O[q=q0+c][d = cb*16+4g+e]; lane-local divide; bf16x4 stores ---
    const float linv = 1.0f / l_run;
    bf16* yr = y + (size_t)(b * T_SEQ + q) * CDIM + h * 64 + 4 * g;
#pragma unroll
    for (int cb = 0; cb < 4; ++cb) {
        bf16x4 ov = { (bf16)(o[cb][0] * linv), (bf16)(o[cb][1] * linv),
                      (bf16)(o[cb][2] * linv), (bf16)(o[cb][3] * linv) };
        *reinterpret_cast<bf16x4*>(yr + cb * 16) = ov;
    }
}

// ---------------- launch ----------------
extern "C" void kernel_launch(void* const* d_in, const int* in_sizes, int n_in,
                              void* d_out, int out_size, void* d_ws, size_t ws_size,
                              hipStream_t stream) {
    const float* x      = (const float*)d_in[0];
    const float* W_attn = (const float*)d_in[1];
    const float* W_proj = (const float*)d_in[2];
    float* out = (float*)d_out;

    char* ws = (char*)d_ws;
    bf16* xb   = (bf16*)(ws);                  //  4096x1024 bf16 =  8 MiB
    bf16* WaT  = (bf16*)(ws + 8388608);        //  3072x1024 bf16 =  6 MiB
    bf16* WpT  = (bf16*)(ws + 14680064);       //  1024x1024 bf16 =  2 MiB
    bf16* qkv  = (bf16*)(ws + 16777216);       //  4096x3072 bf16 = 24 MiB (V third unused)
    bf16* yatt = (bf16*)(ws + 41943040);       //  4096x1024 bf16 =  8 MiB
    bf16* Vt   = (bf16*)(ws + 50331648);       //  2x16x64x2048 bf16 = 8 MiB (own region: no alias with xb)

    cast_f32_bf16_kernel<<<4096, 256, 0, stream>>>(x, xb, 1048576);
    transpose_cast_kernel<<<dim3(48, 16), 256, 0, stream>>>(W_attn, WaT, 1024, 3072);
    transpose_cast_kernel<<<dim3(16, 16), 256, 0, stream>>>(W_proj, WpT, 1024, 1024);

    gemm256_kernel<<<256, 512, 0, stream>>>(xb, WaT, qkv, Vt, 4096, 3072, 1024);
    attn_kernel<<<512, 512, 0, stream>>>(qkv, Vt, yatt);
    gemm_bt_kernel<false><<<dim3(8, 32), 256, 0, stream>>>(yatt, WpT, nullptr, out, 4096, 1024, 1024);
}

// Round 10
// 92.049 us; speedup vs baseline: 1.4938x; 1.1096x over previous
//
#include <hip/hip_runtime.h>

typedef __bf16 bf16;
typedef __bf16 bf16x4 __attribute__((ext_vector_type(4)));
typedef __bf16 bf16x8 __attribute__((ext_vector_type(8)));
typedef float f32x4 __attribute__((ext_vector_type(4)));

#define T_SEQ 2048
#define CDIM  1024
#define QKV_LD 3072
#define MEM   256

// global -> LDS direct DMA, 16B per lane. LDS dest is wave-uniform base + lane*16B.
#define GLOAD_LDS16(gp, lp) __builtin_amdgcn_global_load_lds( \
    (const __attribute__((address_space(1))) unsigned int*)(gp), \
    (__attribute__((address_space(3))) unsigned int*)(lp), 16, 0, 0)

#define BAR() do { __builtin_amdgcn_s_barrier(); asm volatile("" ::: "memory"); } while (0)

// ------------- fused prep: cast x (blocks 0..4095), transpose W_attn (4096..4863),
//               transpose W_proj (4864..5119) -------------
__global__ __launch_bounds__(256) void prep_kernel(const float* __restrict__ x,
                                                   const float* __restrict__ Wa,
                                                   const float* __restrict__ Wp,
                                                   bf16* __restrict__ xb,
                                                   bf16* __restrict__ WaT,
                                                   bf16* __restrict__ WpT) {
    const int bid = blockIdx.x;
    if (bid < 4096) {
        int i = bid * 256 + threadIdx.x;
        float4 v = reinterpret_cast<const float4*>(x)[i];
        bf16x4 o = { (bf16)v.x, (bf16)v.y, (bf16)v.z, (bf16)v.w };
        reinterpret_cast<bf16x4*>(xb)[i] = o;
        return;
    }
    // transpose+cast W[K=1024][N] -> Wt[N][1024]
    const float* W; bf16* Wt; int N, bx, by;
    if (bid < 4864) { W = Wa; Wt = WaT; N = 3072; int idx = bid - 4096; bx = idx % 48; by = idx / 48; }
    else            { W = Wp; Wt = WpT; N = 1024; int idx = bid - 4864; bx = idx % 16; by = idx / 16; }
    __shared__ float tile[64][65];
    const int n0 = bx * 64;
    const int k0 = by * 64;
    const int t  = threadIdx.x;
    const int tr = t >> 4;
    const int tc = (t & 15) * 4;
#pragma unroll
    for (int it = 0; it < 4; ++it) {
        int r = it * 16 + tr;
        float4 v = *reinterpret_cast<const float4*>(&W[(size_t)(k0 + r) * N + n0 + tc]);
        tile[r][tc + 0] = v.x; tile[r][tc + 1] = v.y;
        tile[r][tc + 2] = v.z; tile[r][tc + 3] = v.w;
    }
    __syncthreads();
#pragma unroll
    for (int it = 0; it < 4; ++it) {
        int n = it * 16 + tr;
        bf16x4 o;
#pragma unroll
        for (int j = 0; j < 4; ++j) o[j] = (bf16)tile[tc + j][n];
        *reinterpret_cast<bf16x4*>(&Wt[(size_t)(n0 + n) * 1024 + k0 + tc]) = o;
    }
}

// ------------- 256x192 GEMM, fine-interleaved, V-transposing epilogue (frozen R9) -------------
__global__ __launch_bounds__(512, 1) void gemm256_kernel(const bf16* __restrict__ A,
                                                         const bf16* __restrict__ Bt,
                                                         bf16* __restrict__ Cb,
                                                         bf16* __restrict__ Vt,
                                                         int M, int N, int K) {
    __shared__ bf16 smA[2][256][64];
    __shared__ bf16 smB[2][192][64];
    const int t    = threadIdx.x;
    const int lane = t & 63;
    const int w    = t >> 6;
    const int wm   = (w >> 2) * 128;     // wave row-half
    const int wn   = (w & 3) * 48;       // wave col-quarter (3 frags of 16)
    const int g    = lane >> 4;
    const int r    = lane & 15;

    const int nwg = gridDim.x, cpx = nwg >> 3;           // 256 % 8 == 0 -> bijective
    const int swz = (blockIdx.x & 7) * cpx + (blockIdx.x >> 3);
    const int ntn = N / 192;
    const int m0 = (swz / ntn) * 256;
    const int n0 = (swz % ntn) * 192;

    const bf16* Ab = A  + (size_t)m0 * K;
    const bf16* Bb = Bt + (size_t)n0 * K;
    const int NT = K >> 6;               // K-tiles of 64

#define STAGE_A(bi, u, kt) do { \
        const bf16* _s = Ab + (size_t)((u) * 64 + w * 8 + (lane >> 3)) * K \
                         + (kt) * 64 + ((lane & 7) ^ (lane >> 3)) * 8; \
        GLOAD_LDS16(_s, &smA[bi][(u) * 64 + w * 8][0]); \
    } while (0)
#define STAGE_B(bi, u, kt) do { \
        const bf16* _s = Bb + (size_t)((u) * 64 + w * 8 + (lane >> 3)) * K \
                         + (kt) * 64 + ((lane & 7) ^ (lane >> 3)) * 8; \
        GLOAD_LDS16(_s, &smB[bi][(u) * 64 + w * 8][0]); \
    } while (0)

    const int ch0 = ((g     ) ^ (r & 7)) * 8;   // read-side swizzle (row&7 == r&7)
    const int ch1 = ((g ^ 4) ^ (r & 7)) * 8;

    const f32x4 zero4 = {0.f, 0.f, 0.f, 0.f};
    f32x4 acc[8][3];
#pragma unroll
    for (int i = 0; i < 8; ++i)
#pragma unroll
        for (int j = 0; j < 3; ++j) acc[i][j] = zero4;

    bf16x8 afr0[4][2], afr1[4][2], bfrA[2][2], bfrB[1][2];

#define MGRP(AF, FMB, BF, FNB, NF) do { \
    __builtin_amdgcn_s_setprio(1); \
    _Pragma("unroll") \
    for (int fm2 = 0; fm2 < 4; ++fm2) \
    _Pragma("unroll") \
    for (int fn2 = 0; fn2 < (NF); ++fn2) \
    _Pragma("unroll") \
    for (int kh = 0; kh < 2; ++kh) \
        acc[(FMB)+fm2][(FNB)+fn2] = __builtin_amdgcn_mfma_f32_16x16x32_bf16( \
            AF[fm2][kh], BF[fn2][kh], acc[(FMB)+fm2][(FNB)+fn2], 0, 0, 0); \
    __builtin_amdgcn_s_setprio(0); } while (0)

    // ---- prologue ----
    STAGE_A(0, 0, 0); STAGE_A(0, 1, 0); STAGE_A(0, 2, 0); STAGE_A(0, 3, 0);
    STAGE_B(0, 0, 0); STAGE_B(0, 1, 0); STAGE_B(0, 2, 0);
    STAGE_A(1, 0, 1); STAGE_A(1, 1, 1); STAGE_A(1, 2, 1); STAGE_A(1, 3, 1);
    asm volatile("s_waitcnt vmcnt(4)" ::: "memory");
    __builtin_amdgcn_sched_barrier(0);
    BAR();

    for (int kt = 0; kt < NT; ++kt) {
        const int cur = kt & 1, nxt = cur ^ 1;
#pragma unroll
        for (int i = 0; i < 4; ++i) {
            afr0[i][0] = *reinterpret_cast<const bf16x8*>(&smA[cur][wm + i * 16 + r][ch0]);
            afr0[i][1] = *reinterpret_cast<const bf16x8*>(&smA[cur][wm + i * 16 + r][ch1]);
        }
#pragma unroll
        for (int fn = 0; fn < 2; ++fn) {
            bfrA[fn][0] = *reinterpret_cast<const bf16x8*>(&smB[cur][wn + fn * 16 + r][ch0]);
            bfrA[fn][1] = *reinterpret_cast<const bf16x8*>(&smB[cur][wn + fn * 16 + r][ch1]);
        }
#pragma unroll
        for (int i = 0; i < 4; ++i) {
            afr1[i][0] = *reinterpret_cast<const bf16x8*>(&smA[cur][wm + 64 + i * 16 + r][ch0]);
            afr1[i][1] = *reinterpret_cast<const bf16x8*>(&smA[cur][wm + 64 + i * 16 + r][ch1]);
        }
        bfrB[0][0] = *reinterpret_cast<const bf16x8*>(&smB[cur][wn + 32 + r][ch0]);
        bfrB[0][1] = *reinterpret_cast<const bf16x8*>(&smB[cur][wn + 32 + r][ch1]);
        if (kt + 1 < NT) { STAGE_B(nxt, 0, kt + 1); STAGE_B(nxt, 1, kt + 1); STAGE_B(nxt, 2, kt + 1); }
        __builtin_amdgcn_sched_barrier(0);
        BAR();

        MGRP(afr0, 0, bfrA, 0, 2);
        if (kt + 2 < NT) STAGE_A(cur, 0, kt + 2);
        MGRP(afr1, 4, bfrA, 0, 2);
        if (kt + 2 < NT) { STAGE_A(cur, 1, kt + 2); STAGE_A(cur, 2, kt + 2); }
        MGRP(afr1, 4, bfrB, 2, 1);
        if (kt + 2 < NT) STAGE_A(cur, 3, kt + 2);
        MGRP(afr0, 0, bfrB, 2, 1);

        if (kt >= NT - 2)      { asm volatile("s_waitcnt vmcnt(0)" ::: "memory"); }
        else                   { asm volatile("s_waitcnt vmcnt(4)" ::: "memory"); }
        __builtin_amdgcn_sched_barrier(0);
        BAR();
    }

    // ---- epilogue: Q/K cols -> qkv rows; V cols (>=2048) -> Vt[b][h][d][t] (bf16x4) ----
#pragma unroll
    for (int fm = 0; fm < 8; ++fm)
#pragma unroll
        for (int fn = 0; fn < 3; ++fn) {
            const int col  = n0 + wn + fn * 16 + r;
            const int row0 = m0 + wm + fm * 16 + g * 4;
            if (col < 2 * CDIM) {
#pragma unroll
                for (int e = 0; e < 4; ++e)
                    Cb[(size_t)(row0 + e) * N + col] = (bf16)acc[fm][fn][e];
            } else {
                const int hd = col - 2 * CDIM;
                const int bb = row0 >> 11, tt = row0 & (T_SEQ - 1);
                bf16x4 v = { (bf16)acc[fm][fn][0], (bf16)acc[fm][fn][1],
                             (bf16)acc[fm][fn][2], (bf16)acc[fm][fn][3] };
                *reinterpret_cast<bf16x4*>(&Vt[((size_t)(bb * 16 + (hd >> 6)) * 64 + (hd & 63)) * T_SEQ + tt]) = v;
            }
        }
#undef STAGE_A
#undef STAGE_B
#undef MGRP
}

// ------------- proj GEMM: 128x64 tiles, 512 blocks = 2/CU (occupancy fix) -------------
// C[M][N] f32 = A[M][K]bf16 * Bt[N][K]^T. 4 waves (2Mx2N); wave tile 64x32 (4x2 frags).
// m97 2-barrier structure, BK=32, gload_lds staging (A: 2 issues/wave, B: 1).
__global__ __launch_bounds__(256) void proj_kernel(const bf16* __restrict__ A,
                                                   const bf16* __restrict__ Bt,
                                                   float* __restrict__ Cf,
                                                   int M, int N, int K) {
    __shared__ bf16 As[128 * 32];
    __shared__ bf16 Bs[64 * 32];
    const int t    = threadIdx.x;
    const int lane = t & 63;
    const int w    = t >> 6;
    const int wm   = (w >> 1) * 64;
    const int wn   = (w & 1) * 32;
    const int g    = lane >> 4;
    const int r    = lane & 15;
    const int m0   = blockIdx.y * 128;
    const int n0   = blockIdx.x * 64;

    const bf16* Ab = A  + (size_t)m0 * K;
    const bf16* Bb = Bt + (size_t)n0 * K;
    // A: wave w stages rows [w*32, w*32+32) (2 issues); B: rows [w*16, w*16+16) (1 issue)
    const bf16* Ag0 = Ab + (size_t)(w * 32 + (lane >> 2)) * K + (lane & 3) * 8;
    const bf16* Ag1 = Ab + (size_t)(w * 32 + 16 + (lane >> 2)) * K + (lane & 3) * 8;
    const bf16* Bg0 = Bb + (size_t)(w * 16 + (lane >> 2)) * K + (lane & 3) * 8;

    bf16* ldsA0 = As + (w * 32) * 32;
    bf16* ldsA1 = As + (w * 32 + 16) * 32;
    bf16* ldsB0 = Bs + (w * 16) * 32;

    const f32x4 zero4 = {0.f, 0.f, 0.f, 0.f};
    f32x4 acc[4][2];
#pragma unroll
    for (int i = 0; i < 4; ++i)
#pragma unroll
        for (int j = 0; j < 2; ++j) acc[i][j] = zero4;

    for (int k0 = 0; k0 < K; k0 += 32) {
        __syncthreads();
        GLOAD_LDS16(Ag0 + k0, ldsA0);
        GLOAD_LDS16(Ag1 + k0, ldsA1);
        GLOAD_LDS16(Bg0 + k0, ldsB0);
        __syncthreads();

        bf16x8 af[4], bfr[2];
#pragma unroll
        for (int i = 0; i < 4; ++i)
            af[i]  = *reinterpret_cast<const bf16x8*>(&As[(wm + i * 16 + r) * 32 + g * 8]);
#pragma unroll
        for (int j = 0; j < 2; ++j)
            bfr[j] = *reinterpret_cast<const bf16x8*>(&Bs[(wn + j * 16 + r) * 32 + g * 8]);
#pragma unroll
        for (int i = 0; i < 4; ++i)
#pragma unroll
            for (int j = 0; j < 2; ++j)
                acc[i][j] = __builtin_amdgcn_mfma_f32_16x16x32_bf16(af[i], bfr[j], acc[i][j], 0, 0, 0);
    }

#pragma unroll
    for (int i = 0; i < 4; ++i)
#pragma unroll
        for (int j = 0; j < 2; ++j)
#pragma unroll
            for (int e = 0; e < 4; ++e) {
                int row = m0 + wm + i * 16 + g * 4 + e;
                int col = n0 + wn + j * 16 + r;
                Cf[(size_t)row * N + col] = acc[i][j][e];
            }
}

// ------------- banded flash attention v5 (frozen from R9) -------------
__global__ __launch_bounds__(512) void attn_kernel(const bf16* __restrict__ qkv,
                                                   const bf16* __restrict__ Vt,
                                                   bf16* __restrict__ y) {
    __shared__ bf16 vtl[64 * 384];       // linear, no pad; swizzle via source/read XOR
    const int bid  = blockIdx.x;
    const int bh   = bid >> 4;
    const int qblk = bid & 15;
    const int b = bh >> 4, h = bh & 15;
    const int qb0 = qblk * 128;
    const int wlo = qb0 - 256;           // window start (may be negative)
    const int wv   = threadIdx.x >> 6;   // wave 0..7
    const int lane = threadIdx.x & 63;
    const int g = lane >> 4, c = lane & 15;
    const int q0 = qb0 + wv * 16;
    const int q = q0 + c;
    const float NEG_INF = -__builtin_inff();

    const bf16* base = qkv + (size_t)b * T_SEQ * QKV_LD;
    const bf16* Qb = base + h * 64;
    const bf16* Kb = base + CDIM + h * 64;
    const bf16* Vtb = Vt + (size_t)(b * 16 + h) * 64 * T_SEQ;

#pragma unroll
    for (int i = 0; i < 6; ++i) {
        const int Lb = (wv * 6 + i) * 1024 + lane * 16;  // linear LDS byte this lane covers
        const int d   = Lb / 768;
        const int c16 = (Lb % 768) >> 4;                 // 16B-pair index within row
        int koff = ((2 * c16) ^ (d & 14)) << 2;          // logical elem offset of this 16B
        int gk = wlo + koff;
        gk = gk < 0 ? 0 : gk;                            // clamp (region masked in compute)
        GLOAD_LDS16(Vtb + (size_t)d * T_SEQ + gk, vtl + (wv * 6 + i) * 512);
    }

    const bf16x8 qf0 = *reinterpret_cast<const bf16x8*>(Qb + (size_t)q * QKV_LD + g * 8);
    const bf16x8 qf1 = *reinterpret_cast<const bf16x8*>(Qb + (size_t)q * QKV_LD + 32 + g * 8);

    __syncthreads();

    const f32x4 zero4 = {0.f, 0.f, 0.f, 0.f};
    f32x4 o[4];
#pragma unroll
    for (int cb = 0; cb < 4; ++cb) o[cb] = zero4;
    float m_run = NEG_INF, l_run = 0.f;

#define LOAD_K(J0, K00, K01, K10, K11) do { \
        const int _kr0 = (J0) + c; \
        int _kr1 = (J0) + 16 + c; _kr1 = _kr1 < T_SEQ ? _kr1 : T_SEQ - 1; \
        K00 = *reinterpret_cast<const bf16x8*>(Kb + (size_t)_kr0 * QKV_LD + g * 8); \
        K01 = *reinterpret_cast<const bf16x8*>(Kb + (size_t)_kr0 * QKV_LD + 32 + g * 8); \
        K10 = *reinterpret_cast<const bf16x8*>(Kb + (size_t)_kr1 * QKV_LD + g * 8); \
        K11 = *reinterpret_cast<const bf16x8*>(Kb + (size_t)_kr1 * QKV_LD + 32 + g * 8); \
    } while (0)

    const int jstart = (q0 - MEM > 0) ? (q0 - MEM) : 0;
    bf16x8 kc00, kc01, kc10, kc11;
    LOAD_K(jstart, kc00, kc01, kc10, kc11);

    for (int j0 = jstart; j0 < q0 + 16; j0 += 32) {
        bf16x8 kn00, kn01, kn10, kn11;
        const bool more = (j0 + 32 < q0 + 16);
        if (more) LOAD_K(j0 + 32, kn00, kn01, kn10, kn11);

        f32x4 s0 = __builtin_amdgcn_mfma_f32_16x16x32_bf16(kc00, qf0, zero4, 0, 0, 0);
        s0 = __builtin_amdgcn_mfma_f32_16x16x32_bf16(kc01, qf1, s0, 0, 0, 0);
        f32x4 s1 = __builtin_amdgcn_mfma_f32_16x16x32_bf16(kc10, qf0, zero4, 0, 0, 0);
        s1 = __builtin_amdgcn_mfma_f32_16x16x32_bf16(kc11, qf1, s1, 0, 0, 0);

        float mt = NEG_INF;
#pragma unroll
        for (int e = 0; e < 4; ++e) {
            int k0i = j0 + 4 * g + e;
            int k1i = k0i + 16;
            float v0 = (k0i <= q && k0i >= q - MEM) ? s0[e] * 0.125f : NEG_INF;
            float v1 = (k1i <= q && k1i >= q - MEM) ? s1[e] * 0.125f : NEG_INF;
            s0[e] = v0; s1[e] = v1;
            mt = fmaxf(mt, fmaxf(v0, v1));
        }
        mt = fmaxf(mt, __shfl_xor(mt, 16, 64));
        mt = fmaxf(mt, __shfl_xor(mt, 32, 64));
        const float mnew = fmaxf(m_run, mt);
        const float corr = __expf(m_run - mnew);

        float ps = 0.f;
        bf16x8 pav;
#pragma unroll
        for (int e = 0; e < 4; ++e) {
            float e0 = __expf(s0[e] - mnew);
            float e1 = __expf(s1[e] - mnew);
            ps += e0 + e1;
            pav[e]     = (bf16)e0;
            pav[4 + e] = (bf16)e1;
        }
        ps += __shfl_xor(ps, 16, 64);
        ps += __shfl_xor(ps, 32, 64);
        l_run = l_run * corr + ps;
        m_run = mnew;

#pragma unroll
        for (int cb = 0; cb < 4; ++cb) {
            o[cb][0] *= corr; o[cb][1] *= corr; o[cb][2] *= corr; o[cb][3] *= corr;
        }

        const int jrel = j0 - wlo;
        const int c8a = (jrel + 4 * g) >> 2;       // 8B-chunk index (always 4-elem aligned)
        const int c8b = (c8a + 4 > 95) ? 95 : (c8a + 4);  // overrun => keys fully masked (P=0)
#pragma unroll
        for (int cb = 0; cb < 4; ++cb) {
            const int d = cb * 16 + c;
            const int xx = d & 14;
            const bf16* vrow = vtl + d * 384;
            bf16x4 va  = *reinterpret_cast<const bf16x4*>(vrow + ((c8a ^ xx) << 2));
            bf16x4 vb2 = *reinterpret_cast<const bf16x4*>(vrow + ((c8b ^ xx) << 2));
            bf16x8 vf = { va[0], va[1], va[2], va[3], vb2[0], vb2[1], vb2[2], vb2[3] };
            o[cb] = __builtin_amdgcn_mfma_f32_16x16x32_bf16(vf, pav, o[cb], 0, 0, 0);
        }

        if (more) { kc00 = kn00; kc01 = kn01; kc10 = kn10; kc11 = kn11; }
    }
#undef LOAD_K

    const float linv = 1.0f / l_run;
    bf16* yr = y + (size_t)(b * T_SEQ + q) * CDIM + h * 64 + 4 * g;
#pragma unroll
    for (int cb = 0; cb < 4; ++cb) {
        bf16x4 ov = { (bf16)(o[cb][0] * linv), (bf16)(o[cb][1] * linv),
                      (bf16)(o[cb][2] * linv), (bf16)(o[cb][3] * linv) };
        *reinterpret_cast<bf16x4*>(yr + cb * 16) = ov;
    }
}

// ---------------- launch ----------------
extern "C" void kernel_launch(void* const* d_in, const int* in_sizes, int n_in,
                              void* d_out, int out_size, void* d_ws, size_t ws_size,
                              hipStream_t stream) {
    const float* x      = (const float*)d_in[0];
    const float* W_attn = (const float*)d_in[1];
    const float* W_proj = (const float*)d_in[2];
    float* out = (float*)d_out;

    char* ws = (char*)d_ws;
    bf16* xb   = (bf16*)(ws);                  //  4096x1024 bf16 =  8 MiB
    bf16* WaT  = (bf16*)(ws + 8388608);        //  3072x1024 bf16 =  6 MiB
    bf16* WpT  = (bf16*)(ws + 14680064);       //  1024x1024 bf16 =  2 MiB
    bf16* qkv  = (bf16*)(ws + 16777216);       //  4096x3072 bf16 = 24 MiB (V third unused)
    bf16* yatt = (bf16*)(ws + 41943040);       //  4096x1024 bf16 =  8 MiB
    bf16* Vt   = (bf16*)(ws + 50331648);       //  2x16x64x2048 bf16 = 8 MiB

    prep_kernel<<<5120, 256, 0, stream>>>(x, W_attn, W_proj, xb, WaT, WpT);
    gemm256_kernel<<<256, 512, 0, stream>>>(xb, WaT, qkv, Vt, 4096, 3072, 1024);
    attn_kernel<<<512, 512, 0, stream>>>(qkv, Vt, yatt);
    proj_kernel<<<dim3(16, 32), 256, 0, stream>>>(yatt, WpT, out, 4096, 1024, 1024);
}

// Round 11
// 91.507 us; speedup vs baseline: 1.5027x; 1.0059x over previous
//
#include <hip/hip_runtime.h>

typedef __bf16 bf16;
typedef __bf16 bf16x4 __attribute__((ext_vector_type(4)));
typedef __bf16 bf16x8 __attribute__((ext_vector_type(8)));
typedef float f32x4 __attribute__((ext_vector_type(4)));

#define T_SEQ 2048
#define CDIM  1024
#define QKV_LD 3072
#define MEM   256

// global -> LDS direct DMA, 16B per lane. LDS dest is wave-uniform base + lane*16B.
#define GLOAD_LDS16(gp, lp) __builtin_amdgcn_global_load_lds( \
    (const __attribute__((address_space(1))) unsigned int*)(gp), \
    (__attribute__((address_space(3))) unsigned int*)(lp), 16, 0, 0)

#define BAR() do { __builtin_amdgcn_s_barrier(); asm volatile("" ::: "memory"); } while (0)

// ------------- fused prep: cast x (blocks 0..4095), transpose W_attn (4096..4863),
//               transpose W_proj (4864..5119) -------------
__global__ __launch_bounds__(256) void prep_kernel(const float* __restrict__ x,
                                                   const float* __restrict__ Wa,
                                                   const float* __restrict__ Wp,
                                                   bf16* __restrict__ xb,
                                                   bf16* __restrict__ WaT,
                                                   bf16* __restrict__ WpT) {
    const int bid = blockIdx.x;
    if (bid < 4096) {
        int i = bid * 256 + threadIdx.x;
        float4 v = reinterpret_cast<const float4*>(x)[i];
        bf16x4 o = { (bf16)v.x, (bf16)v.y, (bf16)v.z, (bf16)v.w };
        reinterpret_cast<bf16x4*>(xb)[i] = o;
        return;
    }
    // transpose+cast W[K=1024][N] -> Wt[N][1024]
    const float* W; bf16* Wt; int N, bx, by;
    if (bid < 4864) { W = Wa; Wt = WaT; N = 3072; int idx = bid - 4096; bx = idx % 48; by = idx / 48; }
    else            { W = Wp; Wt = WpT; N = 1024; int idx = bid - 4864; bx = idx % 16; by = idx / 16; }
    __shared__ float tile[64][65];
    const int n0 = bx * 64;
    const int k0 = by * 64;
    const int t  = threadIdx.x;
    const int tr = t >> 4;
    const int tc = (t & 15) * 4;
#pragma unroll
    for (int it = 0; it < 4; ++it) {
        int r = it * 16 + tr;
        float4 v = *reinterpret_cast<const float4*>(&W[(size_t)(k0 + r) * N + n0 + tc]);
        tile[r][tc + 0] = v.x; tile[r][tc + 1] = v.y;
        tile[r][tc + 2] = v.z; tile[r][tc + 3] = v.w;
    }
    __syncthreads();
#pragma unroll
    for (int it = 0; it < 4; ++it) {
        int n = it * 16 + tr;
        bf16x4 o;
#pragma unroll
        for (int j = 0; j < 4; ++j) o[j] = (bf16)tile[tc + j][n];
        *reinterpret_cast<bf16x4*>(&Wt[(size_t)(n0 + n) * 1024 + k0 + tc]) = o;
    }
}

// ------------- 128x192 GEMM, 2 blocks/CU, fine-interleaved, V-transposing epilogue -------------
// Retile of R10's 256x192: grid = (4096/128)*(3072/192) = 512 blocks, LDS 80 KiB ->
// EXACTLY 2 blocks/CU (16 waves/CU). Cross-block overlap hides the barrier/vmcnt drain
// (the only lever that has paid all session). 8 waves (2M x 4N); per-wave C = 64x48.
// Staging units of 64 rows: A=2, B=3 per K-tile; counted vmcnt(2) (= A-units of t+2).
__global__ __launch_bounds__(512, 4) void gemm256_kernel(const bf16* __restrict__ A,
                                                         const bf16* __restrict__ Bt,
                                                         bf16* __restrict__ Cb,
                                                         bf16* __restrict__ Vt,
                                                         int M, int N, int K) {
    __shared__ bf16 smA[2][128][64];
    __shared__ bf16 smB[2][192][64];
    const int t    = threadIdx.x;
    const int lane = t & 63;
    const int w    = t >> 6;
    const int wm   = (w >> 2) * 64;      // wave row-half (2 halves of 64)
    const int wn   = (w & 3) * 48;       // wave col-quarter (3 frags of 16)
    const int g    = lane >> 4;
    const int r    = lane & 15;

    const int nwg = gridDim.x, cpx = nwg >> 3;           // 512 % 8 == 0 -> bijective
    const int swz = (blockIdx.x & 7) * cpx + (blockIdx.x >> 3);
    const int ntn = N / 192;
    const int m0 = (swz / ntn) * 128;
    const int n0 = (swz % ntn) * 192;

    const bf16* Ab = A  + (size_t)m0 * K;
    const bf16* Bb = Bt + (size_t)n0 * K;
    const int NT = K >> 6;               // K-tiles of 64

#define STAGE_A(bi, u, kt) do { \
        const bf16* _s = Ab + (size_t)((u) * 64 + w * 8 + (lane >> 3)) * K \
                         + (kt) * 64 + ((lane & 7) ^ (lane >> 3)) * 8; \
        GLOAD_LDS16(_s, &smA[bi][(u) * 64 + w * 8][0]); \
    } while (0)
#define STAGE_B(bi, u, kt) do { \
        const bf16* _s = Bb + (size_t)((u) * 64 + w * 8 + (lane >> 3)) * K \
                         + (kt) * 64 + ((lane & 7) ^ (lane >> 3)) * 8; \
        GLOAD_LDS16(_s, &smB[bi][(u) * 64 + w * 8][0]); \
    } while (0)

    const int ch0 = ((g     ) ^ (r & 7)) * 8;   // read-side swizzle (row&7 == r&7)
    const int ch1 = ((g ^ 4) ^ (r & 7)) * 8;

    const f32x4 zero4 = {0.f, 0.f, 0.f, 0.f};
    f32x4 acc[4][3];
#pragma unroll
    for (int i = 0; i < 4; ++i)
#pragma unroll
        for (int j = 0; j < 3; ++j) acc[i][j] = zero4;

    bf16x8 afr[4][2], bfrA[2][2], bfrB[1][2];

#define MGRP(BF, FNB, NF) do { \
    __builtin_amdgcn_s_setprio(1); \
    _Pragma("unroll") \
    for (int fm2 = 0; fm2 < 4; ++fm2) \
    _Pragma("unroll") \
    for (int fn2 = 0; fn2 < (NF); ++fn2) \
    _Pragma("unroll") \
    for (int kh = 0; kh < 2; ++kh) \
        acc[fm2][(FNB)+fn2] = __builtin_amdgcn_mfma_f32_16x16x32_bf16( \
            afr[fm2][kh], BF[fn2][kh], acc[fm2][(FNB)+fn2], 0, 0, 0); \
    __builtin_amdgcn_s_setprio(0); } while (0)

    // ---- prologue: T0 all 5 units + T1 A-units (2); wait T0 landed ----
    STAGE_A(0, 0, 0); STAGE_A(0, 1, 0);
    STAGE_B(0, 0, 0); STAGE_B(0, 1, 0); STAGE_B(0, 2, 0);
    STAGE_A(1, 0, 1); STAGE_A(1, 1, 1);
    asm volatile("s_waitcnt vmcnt(2)" ::: "memory");
    __builtin_amdgcn_sched_barrier(0);
    BAR();

    for (int kt = 0; kt < NT; ++kt) {
        const int cur = kt & 1, nxt = cur ^ 1;
        // ---- ds_reads: afr (8) + bfrA (4) + bfrB (2) ----
#pragma unroll
        for (int i = 0; i < 4; ++i) {
            afr[i][0] = *reinterpret_cast<const bf16x8*>(&smA[cur][wm + i * 16 + r][ch0]);
            afr[i][1] = *reinterpret_cast<const bf16x8*>(&smA[cur][wm + i * 16 + r][ch1]);
        }
#pragma unroll
        for (int fn = 0; fn < 2; ++fn) {
            bfrA[fn][0] = *reinterpret_cast<const bf16x8*>(&smB[cur][wn + fn * 16 + r][ch0]);
            bfrA[fn][1] = *reinterpret_cast<const bf16x8*>(&smB[cur][wn + fn * 16 + r][ch1]);
        }
        bfrB[0][0] = *reinterpret_cast<const bf16x8*>(&smB[cur][wn + 32 + r][ch0]);
        bfrB[0][1] = *reinterpret_cast<const bf16x8*>(&smB[cur][wn + 32 + r][ch1]);
        if (kt + 1 < NT) { STAGE_B(nxt, 0, kt + 1); STAGE_B(nxt, 1, kt + 1); STAGE_B(nxt, 2, kt + 1); }
        __builtin_amdgcn_sched_barrier(0);
        BAR();                                // all waves' reads of buf[cur] issued

        // ---- 2 MFMA groups; A-units of tile kt+2 interleaved ----
        MGRP(bfrA, 0, 2);                     // 16 MFMA
        if (kt + 2 < NT) STAGE_A(cur, 0, kt + 2);
        MGRP(bfrB, 2, 1);                     // 8 MFMA
        if (kt + 2 < NT) STAGE_A(cur, 1, kt + 2);

        if (kt >= NT - 2)      { asm volatile("s_waitcnt vmcnt(0)" ::: "memory"); }
        else                   { asm volatile("s_waitcnt vmcnt(2)" ::: "memory"); }
        __builtin_amdgcn_sched_barrier(0);
        BAR();                                // next tile landed; safe to read
    }

    // ---- epilogue: Q/K cols -> qkv rows; V cols (>=2048) -> Vt[b][h][d][t] (bf16x4) ----
#pragma unroll
    for (int fm = 0; fm < 4; ++fm)
#pragma unroll
        for (int fn = 0; fn < 3; ++fn) {
            const int col  = n0 + wn + fn * 16 + r;
            const int row0 = m0 + wm + fm * 16 + g * 4;
            if (col < 2 * CDIM) {
#pragma unroll
                for (int e = 0; e < 4; ++e)
                    Cb[(size_t)(row0 + e) * N + col] = (bf16)acc[fm][fn][e];
            } else {
                const int hd = col - 2 * CDIM;
                const int bb = row0 >> 11, tt = row0 & (T_SEQ - 1);
                bf16x4 v = { (bf16)acc[fm][fn][0], (bf16)acc[fm][fn][1],
                             (bf16)acc[fm][fn][2], (bf16)acc[fm][fn][3] };
                *reinterpret_cast<bf16x4*>(&Vt[((size_t)(bb * 16 + (hd >> 6)) * 64 + (hd & 63)) * T_SEQ + tt]) = v;
            }
        }
#undef STAGE_A
#undef STAGE_B
#undef MGRP
}

// ------------- proj GEMM: 128x64 tiles, 512 blocks = 2/CU (frozen R10) -------------
__global__ __launch_bounds__(256) void proj_kernel(const bf16* __restrict__ A,
                                                   const bf16* __restrict__ Bt,
                                                   float* __restrict__ Cf,
                                                   int M, int N, int K) {
    __shared__ bf16 As[128 * 32];
    __shared__ bf16 Bs[64 * 32];
    const int t    = threadIdx.x;
    const int lane = t & 63;
    const int w    = t >> 6;
    const int wm   = (w >> 1) * 64;
    const int wn   = (w & 1) * 32;
    const int g    = lane >> 4;
    const int r    = lane & 15;
    const int m0   = blockIdx.y * 128;
    const int n0   = blockIdx.x * 64;

    const bf16* Ab = A  + (size_t)m0 * K;
    const bf16* Bb = Bt + (size_t)n0 * K;
    const bf16* Ag0 = Ab + (size_t)(w * 32 + (lane >> 2)) * K + (lane & 3) * 8;
    const bf16* Ag1 = Ab + (size_t)(w * 32 + 16 + (lane >> 2)) * K + (lane & 3) * 8;
    const bf16* Bg0 = Bb + (size_t)(w * 16 + (lane >> 2)) * K + (lane & 3) * 8;

    bf16* ldsA0 = As + (w * 32) * 32;
    bf16* ldsA1 = As + (w * 32 + 16) * 32;
    bf16* ldsB0 = Bs + (w * 16) * 32;

    const f32x4 zero4 = {0.f, 0.f, 0.f, 0.f};
    f32x4 acc[4][2];
#pragma unroll
    for (int i = 0; i < 4; ++i)
#pragma unroll
        for (int j = 0; j < 2; ++j) acc[i][j] = zero4;

    for (int k0 = 0; k0 < K; k0 += 32) {
        __syncthreads();
        GLOAD_LDS16(Ag0 + k0, ldsA0);
        GLOAD_LDS16(Ag1 + k0, ldsA1);
        GLOAD_LDS16(Bg0 + k0, ldsB0);
        __syncthreads();

        bf16x8 af[4], bfr[2];
#pragma unroll
        for (int i = 0; i < 4; ++i)
            af[i]  = *reinterpret_cast<const bf16x8*>(&As[(wm + i * 16 + r) * 32 + g * 8]);
#pragma unroll
        for (int j = 0; j < 2; ++j)
            bfr[j] = *reinterpret_cast<const bf16x8*>(&Bs[(wn + j * 16 + r) * 32 + g * 8]);
#pragma unroll
        for (int i = 0; i < 4; ++i)
#pragma unroll
            for (int j = 0; j < 2; ++j)
                acc[i][j] = __builtin_amdgcn_mfma_f32_16x16x32_bf16(af[i], bfr[j], acc[i][j], 0, 0, 0);
    }

#pragma unroll
    for (int i = 0; i < 4; ++i)
#pragma unroll
        for (int j = 0; j < 2; ++j)
#pragma unroll
            for (int e = 0; e < 4; ++e) {
                int row = m0 + wm + i * 16 + g * 4 + e;
                int col = n0 + wn + j * 16 + r;
                Cf[(size_t)row * N + col] = acc[i][j][e];
            }
}

// ------------- banded flash attention v5 (frozen from R9) -------------
__global__ __launch_bounds__(512) void attn_kernel(const bf16* __restrict__ qkv,
                                                   const bf16* __restrict__ Vt,
                                                   bf16* __restrict__ y) {
    __shared__ bf16 vtl[64 * 384];       // linear, no pad; swizzle via source/read XOR
    const int bid  = blockIdx.x;
    const int bh   = bid >> 4;
    const int qblk = bid & 15;
    const int b = bh >> 4, h = bh & 15;
    const int qb0 = qblk * 128;
    const int wlo = qb0 - 256;           // window start (may be negative)
    const int wv   = threadIdx.x >> 6;   // wave 0..7
    const int lane = threadIdx.x & 63;
    const int g = lane >> 4, c = lane & 15;
    const int q0 = qb0 + wv * 16;
    const int q = q0 + c;
    const float NEG_INF = -__builtin_inff();

    const bf16* base = qkv + (size_t)b * T_SEQ * QKV_LD;
    const bf16* Qb = base + h * 64;
    const bf16* Kb = base + CDIM + h * 64;
    const bf16* Vtb = Vt + (size_t)(b * 16 + h) * 64 * T_SEQ;

#pragma unroll
    for (int i = 0; i < 6; ++i) {
        const int Lb = (wv * 6 + i) * 1024 + lane * 16;  // linear LDS byte this lane covers
        const int d   = Lb / 768;
        const int c16 = (Lb % 768) >> 4;                 // 16B-pair index within row
        int koff = ((2 * c16) ^ (d & 14)) << 2;          // logical elem offset of this 16B
        int gk = wlo + koff;
        gk = gk < 0 ? 0 : gk;                            // clamp (region masked in compute)
        GLOAD_LDS16(Vtb + (size_t)d * T_SEQ + gk, vtl + (wv * 6 + i) * 512);
    }

    const bf16x8 qf0 = *reinterpret_cast<const bf16x8*>(Qb + (size_t)q * QKV_LD + g * 8);
    const bf16x8 qf1 = *reinterpret_cast<const bf16x8*>(Qb + (size_t)q * QKV_LD + 32 + g * 8);

    __syncthreads();

    const f32x4 zero4 = {0.f, 0.f, 0.f, 0.f};
    f32x4 o[4];
#pragma unroll
    for (int cb = 0; cb < 4; ++cb) o[cb] = zero4;
    float m_run = NEG_INF, l_run = 0.f;

#define LOAD_K(J0, K00, K01, K10, K11) do { \
        const int _kr0 = (J0) + c; \
        int _kr1 = (J0) + 16 + c; _kr1 = _kr1 < T_SEQ ? _kr1 : T_SEQ - 1; \
        K00 = *reinterpret_cast<const bf16x8*>(Kb + (size_t)_kr0 * QKV_LD + g * 8); \
        K01 = *reinterpret_cast<const bf16x8*>(Kb + (size_t)_kr0 * QKV_LD + 32 + g * 8); \
        K10 = *reinterpret_cast<const bf16x8*>(Kb + (size_t)_kr1 * QKV_LD + g * 8); \
        K11 = *reinterpret_cast<const bf16x8*>(Kb + (size_t)_kr1 * QKV_LD + 32 + g * 8); \
    } while (0)

    const int jstart = (q0 - MEM > 0) ? (q0 - MEM) : 0;
    bf16x8 kc00, kc01, kc10, kc11;
    LOAD_K(jstart, kc00, kc01, kc10, kc11);

    for (int j0 = jstart; j0 < q0 + 16; j0 += 32) {
        bf16x8 kn00, kn01, kn10, kn11;
        const bool more = (j0 + 32 < q0 + 16);
        if (more) LOAD_K(j0 + 32, kn00, kn01, kn10, kn11);

        f32x4 s0 = __builtin_amdgcn_mfma_f32_16x16x32_bf16(kc00, qf0, zero4, 0, 0, 0);
        s0 = __builtin_amdgcn_mfma_f32_16x16x32_bf16(kc01, qf1, s0, 0, 0, 0);
        f32x4 s1 = __builtin_amdgcn_mfma_f32_16x16x32_bf16(kc10, qf0, zero4, 0, 0, 0);
        s1 = __builtin_amdgcn_mfma_f32_16x16x32_bf16(kc11, qf1, s1, 0, 0, 0);

        float mt = NEG_INF;
#pragma unroll
        for (int e = 0; e < 4; ++e) {
            int k0i = j0 + 4 * g + e;
            int k1i = k0i + 16;
            float v0 = (k0i <= q && k0i >= q - MEM) ? s0[e] * 0.125f : NEG_INF;
            float v1 = (k1i <= q && k1i >= q - MEM) ? s1[e] * 0.125f : NEG_INF;
            s0[e] = v0; s1[e] = v1;
            mt = fmaxf(mt, fmaxf(v0, v1));
        }
        mt = fmaxf(mt, __shfl_xor(mt, 16, 64));
        mt = fmaxf(mt, __shfl_xor(mt, 32, 64));
        const float mnew = fmaxf(m_run, mt);
        const float corr = __expf(m_run - mnew);

        float ps = 0.f;
        bf16x8 pav;
#pragma unroll
        for (int e = 0; e < 4; ++e) {
            float e0 = __expf(s0[e] - mnew);
            float e1 = __expf(s1[e] - mnew);
            ps += e0 + e1;
            pav[e]     = (bf16)e0;
            pav[4 + e] = (bf16)e1;
        }
        ps += __shfl_xor(ps, 16, 64);
        ps += __shfl_xor(ps, 32, 64);
        l_run = l_run * corr + ps;
        m_run = mnew;

#pragma unroll
        for (int cb = 0; cb < 4; ++cb) {
            o[cb][0] *= corr; o[cb][1] *= corr; o[cb][2] *= corr; o[cb][3] *= corr;
        }

        const int jrel = j0 - wlo;
        const int c8a = (jrel + 4 * g) >> 2;       // 8B-chunk index (always 4-elem aligned)
        const int c8b = (c8a + 4 > 95) ? 95 : (c8a + 4);  // overrun => keys fully masked (P=0)
#pragma unroll
        for (int cb = 0; cb < 4; ++cb) {
            const int d = cb * 16 + c;
            const int xx = d & 14;
            const bf16* vrow = vtl + d * 384;
            bf16x4 va  = *reinterpret_cast<const bf16x4*>(vrow + ((c8a ^ xx) << 2));
            bf16x4 vb2 = *reinterpret_cast<const bf16x4*>(vrow + ((c8b ^ xx) << 2));
            bf16x8 vf = { va[0], va[1], va[2], va[3], vb2[0], vb2[1], vb2[2], vb2[3] };
            o[cb] = __builtin_amdgcn_mfma_f32_16x16x32_bf16(vf, pav, o[cb], 0, 0, 0);
        }

        if (more) { kc00 = kn00; kc01 = kn01; kc10 = kn10; kc11 = kn11; }
    }
#undef LOAD_K

    const float linv = 1.0f / l_run;
    bf16* yr = y + (size_t)(b * T_SEQ + q) * CDIM + h * 64 + 4 * g;
#pragma unroll
    for (int cb = 0; cb < 4; ++cb) {
        bf16x4 ov = { (bf16)(o[cb][0] * linv), (bf16)(o[cb][1] * linv),
                      (bf16)(o[cb][2] * linv), (bf16)(o[cb][3] * linv) };
        *reinterpret_cast<bf16x4*>(yr + cb * 16) = ov;
    }
}

// ---------------- launch ----------------
extern "C" void kernel_launch(void* const* d_in, const int* in_sizes, int n_in,
                              void* d_out, int out_size, void* d_ws, size_t ws_size,
                              hipStream_t stream) {
    const float* x      = (const float*)d_in[0];
    const float* W_attn = (const float*)d_in[1];
    const float* W_proj = (const float*)d_in[2];
    float* out = (float*)d_out;

    char* ws = (char*)d_ws;
    bf16* xb   = (bf16*)(ws);                  //  4096x1024 bf16 =  8 MiB
    bf16* WaT  = (bf16*)(ws + 8388608);        //  3072x1024 bf16 =  6 MiB
    bf16* WpT  = (bf16*)(ws + 14680064);       //  1024x1024 bf16 =  2 MiB
    bf16* qkv  = (bf16*)(ws + 16777216);       //  4096x3072 bf16 = 24 MiB (V third unused)
    bf16* yatt = (bf16*)(ws + 41943040);       //  4096x1024 bf16 =  8 MiB
    bf16* Vt   = (bf16*)(ws + 50331648);       //  2x16x64x2048 bf16 = 8 MiB

    prep_kernel<<<5120, 256, 0, stream>>>(x, W_attn, W_proj, xb, WaT, WpT);
    gemm256_kernel<<<512, 512, 0, stream>>>(xb, WaT, qkv, Vt, 4096, 3072, 1024);
    attn_kernel<<<512, 512, 0, stream>>>(qkv, Vt, yatt);
    proj_kernel<<<dim3(16, 32), 256, 0, stream>>>(yatt, WpT, out, 4096, 1024, 1024);
}